// Round 2
// baseline (335.092 us; speedup 1.0000x reference)
//
#include <hip/hip_runtime.h>

#define HIDDEN 2048
#define NHEADS 32
#define NKV 8
#define HD 64
#define BATCH 2
#define SEQ 2048
#define MROWS (BATCH*SEQ)        // 4096
#define KVDIM (NKV*HD)           // 512
#define QKVN (HIDDEN + 2*KVDIM)  // 3072

typedef __bf16 bf16x8 __attribute__((ext_vector_type(8)));
typedef float f32x4 __attribute__((ext_vector_type(4)));

// async global->LDS, 16B per lane; lds base must be wave-uniform (HW: base + lane*16)
__device__ inline void gld16(const __bf16* g, __bf16* l) {
    __builtin_amdgcn_global_load_lds((const __attribute__((address_space(1))) void*)g,
                                     (__attribute__((address_space(3))) void*)l, 16, 0, 0);
}

// ---------------- fused cast fp32 -> bf16 for all 5 tensors ----------------
__global__ __launch_bounds__(256) void cast_all(const float* __restrict__ x,
                                                const float* __restrict__ wq,
                                                const float* __restrict__ wk,
                                                const float* __restrict__ wv,
                                                const float* __restrict__ wo,
                                                __bf16* __restrict__ xb,
                                                __bf16* __restrict__ wqkv,
                                                __bf16* __restrict__ wob,
                                                float qscale) {
    int blk = blockIdx.x;
    const float* src; __bf16* dst; float sc = 1.0f; size_t off;
    if (blk < 8192)        { src = x;  dst = xb;   off = (size_t)blk * 1024; }
    else if (blk < 12288)  { src = wq; dst = wqkv; off = (size_t)(blk - 8192) * 1024; sc = qscale; }
    else if (blk < 13312)  { src = wk; dst = wqkv + (size_t)HIDDEN * HIDDEN; off = (size_t)(blk - 12288) * 1024; }
    else if (blk < 14336)  { src = wv; dst = wqkv + (size_t)(HIDDEN + KVDIM) * HIDDEN; off = (size_t)(blk - 13312) * 1024; }
    else                   { src = wo; dst = wob;  off = (size_t)(blk - 14336) * 1024; }
    size_t i4 = off + (size_t)threadIdx.x * 4;
    float4 f = *(const float4*)(src + i4);
    dst[i4 + 0] = (__bf16)(f.x * sc);
    dst[i4 + 1] = (__bf16)(f.y * sc);
    dst[i4 + 2] = (__bf16)(f.z * sc);
    dst[i4 + 3] = (__bf16)(f.w * sc);
}

__device__ inline void store_val(__bf16* C, size_t idx, float v) { C[idx] = (__bf16)v; }
__device__ inline void store_val(float* C, size_t idx, float v) { C[idx] = v; }

// ---------------- GEMM: C = A(M,K) @ B(N,K)^T; double-buffered LDS, BK=32 -----
template <typename OutT>
__global__ __launch_bounds__(256) void gemm128(const __bf16* __restrict__ A,
                                               const __bf16* __restrict__ B,
                                               OutT* __restrict__ C,
                                               int M, int N, int K) {
    __shared__ __bf16 As[2][128][32];
    __shared__ __bf16 Bs[2][128][32];
    const int tid  = threadIdx.x;
    const int lane = tid & 63;
    const int w    = tid >> 6;
    const int col  = lane & 15;
    const int quad = lane >> 4;
    const int m0 = blockIdx.y * 128;
    const int n0 = blockIdx.x * 128;
    const int wm = (w >> 1) * 64;
    const int wn = (w & 1) * 64;

    f32x4 acc[4][4];
    #pragma unroll
    for (int i = 0; i < 4; i++)
        #pragma unroll
        for (int j = 0; j < 4; j++) acc[i][j] = (f32x4){0.f,0.f,0.f,0.f};

    const int lrow = lane >> 2;        // 0..15
    const int lcol = (lane & 3) * 8;   // 0,8,16,24

    auto stage = [&](int k0, int buf) {
        #pragma unroll
        for (int c = 0; c < 4; c++) {
            int chunk = w * 4 + c;
            if (chunk < 8) {
                const __bf16* g = A + (size_t)(m0 + chunk*16 + lrow) * K + k0 + lcol;
                gld16(g, &As[buf][chunk*16][0]);
            } else {
                int bc = chunk - 8;
                const __bf16* g = B + (size_t)(n0 + bc*16 + lrow) * K + k0 + lcol;
                gld16(g, &Bs[buf][bc*16][0]);
            }
        }
    };

    const int nk = K / 32;
    stage(0, 0);
    for (int ki = 0; ki < nk; ki++) {
        const int buf = ki & 1;
        __syncthreads();                      // drains stage(ki) DMA; frees buf^1
        if (ki + 1 < nk) stage((ki + 1) * 32, buf ^ 1);   // overlaps compute below

        bf16x8 af[4], bfr[4];
        #pragma unroll
        for (int i = 0; i < 4; i++) af[i]  = *(const bf16x8*)&As[buf][wm + i*16 + col][quad*8];
        #pragma unroll
        for (int j = 0; j < 4; j++) bfr[j] = *(const bf16x8*)&Bs[buf][wn + j*16 + col][quad*8];
        #pragma unroll
        for (int i = 0; i < 4; i++)
            #pragma unroll
            for (int j = 0; j < 4; j++)
                acc[i][j] = __builtin_amdgcn_mfma_f32_16x16x32_bf16(af[i], bfr[j], acc[i][j], 0, 0, 0);
    }

    #pragma unroll
    for (int i = 0; i < 4; i++) {
        #pragma unroll
        for (int r = 0; r < 4; r++) {
            int mrow = m0 + wm + i*16 + quad*4 + r;
            size_t base = (size_t)mrow * N + n0 + wn;
            #pragma unroll
            for (int j = 0; j < 4; j++)
                store_val(C, base + j*16 + col, acc[i][j][r]);
        }
    }
}

// ---------------- V transpose: VT[kvh*64+d][b*S+s] = QKV[b*S+s][2560 + kvh*64+d] ----
__global__ __launch_bounds__(256) void transpose_v(const __bf16* __restrict__ QKV,
                                                   __bf16* __restrict__ VT) {
    __shared__ __bf16 tile[64][72];
    const int r0 = blockIdx.x * 64;
    const int s0 = blockIdx.y * 64;
    const int t  = threadIdx.x;
    #pragma unroll
    for (int cc = 0; cc < 2; cc++) {
        int c = t + cc * 256;
        int i = c >> 3;
        int j8 = (c & 7) * 8;
        bf16x8 v = *(const bf16x8*)(QKV + (size_t)(s0 + i) * QKVN + (HIDDEN + KVDIM) + r0 + j8);
        *(bf16x8*)&tile[i][j8] = v;
    }
    __syncthreads();
    #pragma unroll
    for (int cc = 0; cc < 2; cc++) {
        int c = t + cc * 256;
        int d = c >> 3;
        int sc = (c & 7) * 8;
        bf16x8 vv;
        #pragma unroll
        for (int j = 0; j < 8; j++) vv[j] = tile[sc + j][d];
        *(bf16x8*)(VT + (size_t)(r0 + d) * MROWS + s0 + sc) = vv;
    }
}

// ---------------- flash attention: complementary pairs, 3-buffer K/V pipeline ----
// Block = 4 waves, q-tiles p and 31-p (64 rows each); wave owns 16 rows of each.
// p is REMAPPED from blockIdx so the 4 blocks co-resident on a CU (bids equal
// mod 256 under round-robin dispatch) get p, p+4, p+8, p+12 instead of the same
// p: per-CU iteration sum drops from worst-case 4*64 to <=208 (load balance).
// K-tile 32. Ks/Vs triple-buffered; raw s_barrier + counted s_waitcnt vmcnt(2).
// Pt (P scratch for the A-fragment relayout) is a tight [32][32] tile with a
// chunk-level XOR swizzle: element chunk c2=(idx>>3) stored at c2^hash(row),
// hash(row)=(row&3)^((row>>2)&3). Conflict-free for both the b16 writes
// (rows 4 apart now hit distinct banks) and the b128 reads (16B-aligned,
// rows 1 apart spread over all 32 banks) -- this was the entire 7.5M
// SQ_LDS_BANK_CONFLICT source (K/V reads measured zero-conflict).
// Q pre-scaled by (1/8)*log2(e); fixed-max exp2 softmax; row sums via ones-MFMA.
__global__ __launch_bounds__(256) void flash_attn(const __bf16* __restrict__ QKV,
                                                  const __bf16* __restrict__ VT,
                                                  __bf16* __restrict__ O) {
    const int bid  = blockIdx.x;
    const int p    = ((bid & 15) + 4 * ((bid >> 8) & 3)) & 15;  // balanced remap
    const int head = (bid >> 4) & 31;
    const int b    = bid >> 9;
    const int kvh  = head >> 2;
    const int tid  = threadIdx.x;
    const int lane = tid & 63;
    const int w    = tid >> 6;
    const int col  = lane & 15;
    const int quad = lane >> 4;

    const int qbL = p * 64 + w * 16;          // light tile rows
    const int qbH = (31 - p) * 64 + w * 16;   // heavy tile rows
    const int np32 = (p + 1) * 2;             // light k-tiles (32-granular)
    const int nh32 = (32 - p) * 2;            // heavy k-tiles = loop length (>=34)

    __shared__ __bf16 Ks[3][2][32][32];  // [buf][d-half][kpos][d32]  12 KB
    __shared__ __bf16 Vs[3][64][32];     // [buf][d][kpos32]          12 KB
    __shared__ __bf16 Pt[4][32][32];     // per-wave P, chunk-XOR swizzled  8 KB

    const size_t qL = (size_t)(b * SEQ + qbL + col) * QKVN + head * HD;
    const size_t qH = (size_t)(b * SEQ + qbH + col) * QKVN + head * HD;
    bf16x8 aqL0 = *(const bf16x8*)(QKV + qL + quad * 8);
    bf16x8 aqL1 = *(const bf16x8*)(QKV + qL + 32 + quad * 8);
    bf16x8 aqH0 = *(const bf16x8*)(QKV + qH + quad * 8);
    bf16x8 aqH1 = *(const bf16x8*)(QKV + qH + 32 + quad * 8);

    bf16x8 ones;
    #pragma unroll
    for (int j = 0; j < 8; j++) ones[j] = (__bf16)1.0f;

    f32x4 oL[4], oH[4];
    #pragma unroll
    for (int dn = 0; dn < 4; dn++) { oL[dn] = (f32x4){0.f,0.f,0.f,0.f}; oH[dn] = (f32x4){0.f,0.f,0.f,0.f}; }
    f32x4 lsumL = (f32x4){0.f,0.f,0.f,0.f};
    f32x4 lsumH = (f32x4){0.f,0.f,0.f,0.f};

    const int lrow = lane >> 2;                       // 0..15 (staging row)
    const int srcc8 = (((lane & 3) ^ (lrow & 3)) * 8); // swizzled source chunk (K/V)
    const int swz   = (quad ^ (col & 3)) * 8;          // swizzled K/V read chunk
    // Pt read chunk: quad ^ hash(row), hash(row)=(row&3)^((row>>2)&3); identical
    // for row=col and row=16+col.
    const int rswz  = (quad ^ (col & 3) ^ ((col >> 2) & 3)) * 8;
    const size_t bS = (size_t)b * SEQ;

    // Hoisted per-lane stage pointers (advance by constant stride per tile).
    // Waves 0,1 stage K d-halves 0,1 (both kpos-halves); waves 2,3 stage V d 0-31 / 32-63.
    const __bf16 *g0, *g1;
    size_t gstep;
    if (w < 2) {
        g0 = QKV + (bS + lrow) * QKVN + HIDDEN + kvh * HD + w * 32 + srcc8;
        g1 = g0 + (size_t)16 * QKVN;
        gstep = (size_t)32 * QKVN;
    } else {
        g0 = VT + (size_t)(kvh * HD + (w - 2) * 32 + lrow) * MROWS + bS + srcc8;
        g1 = g0 + (size_t)16 * MROWS;
        gstep = 32;
    }

    auto stage = [&](int sb) {
        if (w < 2) {
            gld16(g0, &Ks[sb][w][0][0]);
            gld16(g1, &Ks[sb][w][16][0]);
        } else {
            gld16(g0, &Vs[sb][(w - 2) * 32][0]);
            gld16(g1, &Vs[sb][(w - 2) * 32 + 16][0]);
        }
        g0 += gstep; g1 += gstep;
    };

    stage(0);
    stage(1);
    int cur = 0, nx2 = 2;
    for (int kt = 0; kt < nh32; kt++) {
        const int kbase = kt * 32;
        const bool dual = (kt < np32);        // wave-uniform
        // own stage(kt) landed (kt+1 still in flight); tail iterations drain
        if (kt + 1 < nh32) { __asm__ volatile("s_waitcnt vmcnt(2)" ::: "memory"); }
        else               { __asm__ volatile("s_waitcnt vmcnt(0)" ::: "memory"); }
        __builtin_amdgcn_s_barrier();         // all waves' stage(kt) visible
        __asm__ volatile("" ::: "memory");
        if (kt + 2 < nh32) stage(nx2);        // overwrites (kt-1)%3: safe post-barrier

        // S = Q K^T (16x32 per tile); bk fragments shared between H and L
        f32x4 sH[2], sL[2];
        #pragma unroll
        for (int j = 0; j < 2; j++) { sH[j] = (f32x4){0.f,0.f,0.f,0.f}; sL[j] = (f32x4){0.f,0.f,0.f,0.f}; }
        __builtin_amdgcn_s_setprio(1);
        #pragma unroll
        for (int j = 0; j < 2; j++) {
            bf16x8 bk0 = *(const bf16x8*)&Ks[cur][0][j*16 + col][swz];
            bf16x8 bk1 = *(const bf16x8*)&Ks[cur][1][j*16 + col][swz];
            sH[j] = __builtin_amdgcn_mfma_f32_16x16x32_bf16(aqH0, bk0, sH[j], 0, 0, 0);
            sH[j] = __builtin_amdgcn_mfma_f32_16x16x32_bf16(aqH1, bk1, sH[j], 0, 0, 0);
            if (dual) {
                sL[j] = __builtin_amdgcn_mfma_f32_16x16x32_bf16(aqL0, bk0, sL[j], 0, 0, 0);
                sL[j] = __builtin_amdgcn_mfma_f32_16x16x32_bf16(aqL1, bk1, sL[j], 0, 0, 0);
            }
        }
        __builtin_amdgcn_s_setprio(0);

        // diagonal masking (wave-uniform branches; only last 2 tiles intersect)
        if (kt >= nh32 - 2) {
            #pragma unroll
            for (int r = 0; r < 4; r++) {
                int qrow = qbH + quad*4 + r;
                #pragma unroll
                for (int j = 0; j < 2; j++)
                    if (kbase + j*16 + col > qrow) sH[j][r] = -1e30f;
            }
        }
        if (dual && kt >= np32 - 2) {
            #pragma unroll
            for (int r = 0; r < 4; r++) {
                int qrow = qbL + quad*4 + r;
                #pragma unroll
                for (int j = 0; j < 2; j++)
                    if (kbase + j*16 + col > qrow) sL[j][r] = -1e30f;
            }
        }

        // P -> Pt with chunk-XOR swizzle: element (j*16+col) of row pr stored at
        // chunk (j*2 + (col>>3)) ^ (r ^ quad)   [hash(pr) = r^quad], offset col&7
        #pragma unroll
        for (int r = 0; r < 4; r++) {
            int pr = quad*4 + r;
            #pragma unroll
            for (int j = 0; j < 2; j++) {
                int idx = (((j*2 + (col >> 3)) ^ r ^ quad) * 8) + (col & 7);
                Pt[w][pr][idx] = (__bf16)__builtin_amdgcn_exp2f(sH[j][r]);
            }
        }
        if (dual) {
            #pragma unroll
            for (int r = 0; r < 4; r++) {
                int pr = quad*4 + r;
                #pragma unroll
                for (int j = 0; j < 2; j++) {
                    int idx = (((j*2 + (col >> 3)) ^ r ^ quad) * 8) + (col & 7);
                    Pt[w][16 + pr][idx] = (__bf16)__builtin_amdgcn_exp2f(sL[j][r]);
                }
            }
        }

        // wave-local LDS roundtrip (per-wave buffer: lgkm drain suffices)
        __asm__ volatile("s_waitcnt lgkmcnt(0)" ::: "memory");
        bf16x8 apH = *(const bf16x8*)&Pt[w][col][rswz];
        __builtin_amdgcn_s_setprio(1);
        lsumH = __builtin_amdgcn_mfma_f32_16x16x32_bf16(apH, ones, lsumH, 0, 0, 0);
        bf16x8 apL;
        if (dual) {
            apL = *(const bf16x8*)&Pt[w][16 + col][rswz];
            lsumL = __builtin_amdgcn_mfma_f32_16x16x32_bf16(apL, ones, lsumL, 0, 0, 0);
        }

        #pragma unroll
        for (int dn = 0; dn < 4; dn++) {
            bf16x8 bv = *(const bf16x8*)&Vs[cur][dn*16 + col][swz];
            oH[dn] = __builtin_amdgcn_mfma_f32_16x16x32_bf16(apH, bv, oH[dn], 0, 0, 0);
            if (dual)
                oL[dn] = __builtin_amdgcn_mfma_f32_16x16x32_bf16(apL, bv, oL[dn], 0, 0, 0);
        }
        __builtin_amdgcn_s_setprio(0);

        cur = (cur == 2) ? 0 : cur + 1;
        nx2 = (nx2 == 2) ? 0 : nx2 + 1;
    }

    #pragma unroll
    for (int r = 0; r < 4; r++) {
        float invL = 1.0f / lsumL[r];
        float invH = 1.0f / lsumH[r];
        __bf16* opL = O + (size_t)(b * SEQ + qbL + quad*4 + r) * HIDDEN + head * HD;
        __bf16* opH = O + (size_t)(b * SEQ + qbH + quad*4 + r) * HIDDEN + head * HD;
        #pragma unroll
        for (int dn = 0; dn < 4; dn++) {
            opL[dn*16 + col] = (__bf16)(oL[dn][r] * invL);
            opH[dn*16 + col] = (__bf16)(oH[dn][r] * invH);
        }
    }
}

// ---------------- launch ----------------
extern "C" void kernel_launch(void* const* d_in, const int* in_sizes, int n_in,
                              void* d_out, int out_size, void* d_ws, size_t ws_size,
                              hipStream_t stream) {
    const float* x  = (const float*)d_in[0];
    const float* Wq = (const float*)d_in[1];
    const float* Wk = (const float*)d_in[2];
    const float* Wv = (const float*)d_in[3];
    const float* Wo = (const float*)d_in[4];
    float* out = (float*)d_out;

    __bf16* p    = (__bf16*)d_ws;
    __bf16* xb   = p; p += (size_t)MROWS * HIDDEN;
    __bf16* wqkv = p; p += (size_t)QKVN * HIDDEN;
    __bf16* wob  = p; p += (size_t)HIDDEN * HIDDEN;
    __bf16* qkv  = p; p += (size_t)MROWS * QKVN;
    __bf16* vt   = p; p += (size_t)KVDIM * MROWS;
    __bf16* aob  = xb;   // alias: x not needed post-projection

    const float qscale = 0.125f * 1.4426950408889634f;
    cast_all<<<18432, 256, 0, stream>>>(x, Wq, Wk, Wv, Wo, xb, wqkv, wob, qscale);

    dim3 blk(256);
    gemm128<__bf16><<<dim3(QKVN/128, MROWS/128), blk, 0, stream>>>(xb, wqkv, qkv, MROWS, QKVN, HIDDEN);
    transpose_v<<<dim3(KVDIM/64, MROWS/64), blk, 0, stream>>>(qkv, vt);
    flash_attn<<<BATCH * NHEADS * (SEQ/128), blk, 0, stream>>>(qkv, vt, aob);
    gemm128<float><<<dim3(HIDDEN/128, MROWS/128), blk, 0, stream>>>(aob, wob, out, MROWS, HIDDEN, HIDDEN);
}

// Round 3
// 312.652 us; speedup vs baseline: 1.0718x; 1.0718x over previous
//
#include <hip/hip_runtime.h>

#define HIDDEN 2048
#define NHEADS 32
#define NKV 8
#define HD 64
#define BATCH 2
#define SEQ 2048
#define MROWS (BATCH*SEQ)        // 4096
#define KVDIM (NKV*HD)           // 512
#define QKVN (HIDDEN + 2*KVDIM)  // 3072

typedef __bf16 bf16x8 __attribute__((ext_vector_type(8)));
typedef __bf16 bf16x4 __attribute__((ext_vector_type(4)));
typedef float f32x4 __attribute__((ext_vector_type(4)));
typedef short s16x4 __attribute__((ext_vector_type(4)));
typedef short s16x8 __attribute__((ext_vector_type(8)));

__device__ inline f32x4 mfma32(bf16x8 a, bf16x8 b, f32x4 c) {
    return __builtin_amdgcn_mfma_f32_16x16x32_bf16(a, b, c, 0, 0, 0);
}
__device__ inline f32x4 mfma16(s16x4 a, s16x4 b, f32x4 c) {
    return __builtin_amdgcn_mfma_f32_16x16x16bf16_1k(a, b, c, 0, 0, 0);
}

// async global->LDS, 16B per lane; lds base must be wave-uniform (HW: base + lane*16)
__device__ inline void gld16(const __bf16* g, __bf16* l) {
    __builtin_amdgcn_global_load_lds((const __attribute__((address_space(1))) void*)g,
                                     (__attribute__((address_space(3))) void*)l, 16, 0, 0);
}

// ---------------- fused cast fp32 -> bf16 for all 5 tensors ----------------
__global__ __launch_bounds__(256) void cast_all(const float* __restrict__ x,
                                                const float* __restrict__ wq,
                                                const float* __restrict__ wk,
                                                const float* __restrict__ wv,
                                                const float* __restrict__ wo,
                                                __bf16* __restrict__ xb,
                                                __bf16* __restrict__ wqkv,
                                                __bf16* __restrict__ wob,
                                                float qscale) {
    int blk = blockIdx.x;
    const float* src; __bf16* dst; float sc = 1.0f; size_t off;
    if (blk < 8192)        { src = x;  dst = xb;   off = (size_t)blk * 1024; }
    else if (blk < 12288)  { src = wq; dst = wqkv; off = (size_t)(blk - 8192) * 1024; sc = qscale; }
    else if (blk < 13312)  { src = wk; dst = wqkv + (size_t)HIDDEN * HIDDEN; off = (size_t)(blk - 12288) * 1024; }
    else if (blk < 14336)  { src = wv; dst = wqkv + (size_t)(HIDDEN + KVDIM) * HIDDEN; off = (size_t)(blk - 13312) * 1024; }
    else                   { src = wo; dst = wob;  off = (size_t)(blk - 14336) * 1024; }
    size_t i4 = off + (size_t)threadIdx.x * 4;
    float4 f = *(const float4*)(src + i4);
    dst[i4 + 0] = (__bf16)(f.x * sc);
    dst[i4 + 1] = (__bf16)(f.y * sc);
    dst[i4 + 2] = (__bf16)(f.z * sc);
    dst[i4 + 3] = (__bf16)(f.w * sc);
}

__device__ inline void store_val(__bf16* C, size_t idx, float v) { C[idx] = (__bf16)v; }
__device__ inline void store_val(float* C, size_t idx, float v) { C[idx] = v; }

// ---------------- GEMM: C = A(M,K) @ B(N,K)^T; double-buffered LDS, BK=32 -----
template <typename OutT>
__global__ __launch_bounds__(256) void gemm128(const __bf16* __restrict__ A,
                                               const __bf16* __restrict__ B,
                                               OutT* __restrict__ C,
                                               int M, int N, int K) {
    __shared__ __bf16 As[2][128][32];
    __shared__ __bf16 Bs[2][128][32];
    const int tid  = threadIdx.x;
    const int lane = tid & 63;
    const int w    = tid >> 6;
    const int col  = lane & 15;
    const int quad = lane >> 4;
    const int m0 = blockIdx.y * 128;
    const int n0 = blockIdx.x * 128;
    const int wm = (w >> 1) * 64;
    const int wn = (w & 1) * 64;

    f32x4 acc[4][4];
    #pragma unroll
    for (int i = 0; i < 4; i++)
        #pragma unroll
        for (int j = 0; j < 4; j++) acc[i][j] = (f32x4){0.f,0.f,0.f,0.f};

    const int lrow = lane >> 2;        // 0..15
    const int lcol = (lane & 3) * 8;   // 0,8,16,24

    auto stage = [&](int k0, int buf) {
        #pragma unroll
        for (int c = 0; c < 4; c++) {
            int chunk = w * 4 + c;
            if (chunk < 8) {
                const __bf16* g = A + (size_t)(m0 + chunk*16 + lrow) * K + k0 + lcol;
                gld16(g, &As[buf][chunk*16][0]);
            } else {
                int bc = chunk - 8;
                const __bf16* g = B + (size_t)(n0 + bc*16 + lrow) * K + k0 + lcol;
                gld16(g, &Bs[buf][bc*16][0]);
            }
        }
    };

    const int nk = K / 32;
    stage(0, 0);
    for (int ki = 0; ki < nk; ki++) {
        const int buf = ki & 1;
        __syncthreads();                      // drains stage(ki) DMA; frees buf^1
        if (ki + 1 < nk) stage((ki + 1) * 32, buf ^ 1);   // overlaps compute below

        bf16x8 af[4], bfr[4];
        #pragma unroll
        for (int i = 0; i < 4; i++) af[i]  = *(const bf16x8*)&As[buf][wm + i*16 + col][quad*8];
        #pragma unroll
        for (int j = 0; j < 4; j++) bfr[j] = *(const bf16x8*)&Bs[buf][wn + j*16 + col][quad*8];
        #pragma unroll
        for (int i = 0; i < 4; i++)
            #pragma unroll
            for (int j = 0; j < 4; j++)
                acc[i][j] = __builtin_amdgcn_mfma_f32_16x16x32_bf16(af[i], bfr[j], acc[i][j], 0, 0, 0);
    }

    #pragma unroll
    for (int i = 0; i < 4; i++) {
        #pragma unroll
        for (int r = 0; r < 4; r++) {
            int mrow = m0 + wm + i*16 + quad*4 + r;
            size_t base = (size_t)mrow * N + n0 + wn;
            #pragma unroll
            for (int j = 0; j < 4; j++)
                store_val(C, base + j*16 + col, acc[i][j][r]);
        }
    }
}

// ---------------- V transpose with k-order permutation -----------------------
// VT[d][32-block B][o] = V[s = 32B + sigma(o)][d], sigma(o): o=Q*8+j*4+e -> j*16+Q*4+e.
// This makes a single ds_read_b128 at [d][quad*8] in flash yield BOTH 16x16x16
// B-fragments (j=0 low 4, j=1 high 4) with k=quad*4+e, uniform bank spread.
__global__ __launch_bounds__(256) void transpose_v(const __bf16* __restrict__ QKV,
                                                   __bf16* __restrict__ VT) {
    __shared__ __bf16 tile[64][72];
    const int r0 = blockIdx.x * 64;
    const int s0 = blockIdx.y * 64;
    const int t  = threadIdx.x;
    #pragma unroll
    for (int cc = 0; cc < 2; cc++) {
        int c = t + cc * 256;
        int i = c >> 3;
        int j8 = (c & 7) * 8;
        bf16x8 v = *(const bf16x8*)(QKV + (size_t)(s0 + i) * QKVN + (HIDDEN + KVDIM) + r0 + j8);
        *(bf16x8*)&tile[i][j8] = v;
    }
    __syncthreads();
    #pragma unroll
    for (int cc = 0; cc < 2; cc++) {
        int c = t + cc * 256;
        int d = c >> 3;
        int m = c & 7;                 // output 8-elem chunk within 64 s-positions
        bf16x8 vv;
        #pragma unroll
        for (int tt = 0; tt < 8; tt++) {
            // inverse perm: out offset o=8m+tt -> s_local = (m>>2)*32 + (tt>>2)*16 + (m&3)*4 + (tt&3)
            int sl = (m >> 2) * 32 + (tt >> 2) * 16 + (m & 3) * 4 + (tt & 3);
            vv[tt] = tile[sl][d];
        }
        *(bf16x8*)(VT + (size_t)(r0 + d) * MROWS + s0 + m * 8) = vv;
    }
}

// ---------------- flash attention: swapped-QK^T, in-register P, 3-buf K/V ----
// Block = 4 waves, q-tiles p and 31-p (64 rows each); wave owns 16 rows of each.
// QK^T computed as mfma(K, Q) (A/B fragments have identical lane layouts): lane
// holds S[q=qb+col][k=kbase+j*16+quad*4+r] -- which IS the A-fragment layout of
// mfma_f32_16x16x16bf16_1k (k=quad*4+e). So P = exp2(S) is packed to bf16
// IN-REGISTER and fed straight to PV + ones-rowsum MFMAs: the former
// P->LDS->lgkmcnt(0)->LDS->reg round-trip (~200+ cy on the per-iteration
// critical chain, plus all measured bank conflicts) is deleted entirely.
// V is staged in sigma-permuted k-order (see transpose_v) so one b128 read
// yields both j fragments. Row sums keep the old layout via ones-MFMA (K=16),
// so the epilogue and all rounding semantics are unchanged.
// Ks/Vs triple-buffered; raw s_barrier + counted s_waitcnt vmcnt(2). LDS 24 KB.
// Q pre-scaled by (1/8)*log2(e); fixed-max exp2 softmax.
__global__ __launch_bounds__(256) void flash_attn(const __bf16* __restrict__ QKV,
                                                  const __bf16* __restrict__ VT,
                                                  __bf16* __restrict__ O) {
    const int bid  = blockIdx.x;
    const int p    = ((bid & 15) + 4 * ((bid >> 8) & 3)) & 15;  // balanced remap
    const int head = (bid >> 4) & 31;
    const int b    = bid >> 9;
    const int kvh  = head >> 2;
    const int tid  = threadIdx.x;
    const int lane = tid & 63;
    const int w    = tid >> 6;
    const int col  = lane & 15;
    const int quad = lane >> 4;

    const int qbL = p * 64 + w * 16;          // light tile rows
    const int qbH = (31 - p) * 64 + w * 16;   // heavy tile rows
    const int np32 = (p + 1) * 2;             // light k-tiles (32-granular)
    const int nh32 = (32 - p) * 2;            // heavy k-tiles = loop length (>=34)

    __shared__ __bf16 Ks[3][2][32][32];  // [buf][d-half][kpos][d32]  12 KB
    __shared__ __bf16 Vs[3][64][32];     // [buf][d][k-perm o]        12 KB

    const size_t qL = (size_t)(b * SEQ + qbL + col) * QKVN + head * HD;
    const size_t qH = (size_t)(b * SEQ + qbH + col) * QKVN + head * HD;
    bf16x8 aqL0 = *(const bf16x8*)(QKV + qL + quad * 8);
    bf16x8 aqL1 = *(const bf16x8*)(QKV + qL + 32 + quad * 8);
    bf16x8 aqH0 = *(const bf16x8*)(QKV + qH + quad * 8);
    bf16x8 aqH1 = *(const bf16x8*)(QKV + qH + 32 + quad * 8);

    const s16x4 ones4 = { (short)0x3F80, (short)0x3F80, (short)0x3F80, (short)0x3F80 };

    f32x4 oL[4], oH[4];
    #pragma unroll
    for (int dn = 0; dn < 4; dn++) { oL[dn] = (f32x4){0.f,0.f,0.f,0.f}; oH[dn] = (f32x4){0.f,0.f,0.f,0.f}; }
    f32x4 lsumL = (f32x4){0.f,0.f,0.f,0.f};
    f32x4 lsumH = (f32x4){0.f,0.f,0.f,0.f};

    const int lrow = lane >> 2;                        // 0..15 (staging row)
    const int srcc8 = (((lane & 3) ^ (lrow & 3)) * 8); // swizzled source chunk (K)
    const int swz   = (quad ^ (col & 3)) * 8;          // swizzled K read chunk
    const size_t bS = (size_t)b * SEQ;

    // Hoisted per-lane stage pointers (advance by constant stride per tile).
    // Waves 0,1 stage K d-halves 0,1; waves 2,3 stage V d 0-31 / 32-63 (linear order).
    const __bf16 *g0, *g1;
    size_t gstep;
    if (w < 2) {
        g0 = QKV + (bS + lrow) * QKVN + HIDDEN + kvh * HD + w * 32 + srcc8;
        g1 = g0 + (size_t)16 * QKVN;
        gstep = (size_t)32 * QKVN;
    } else {
        g0 = VT + (size_t)(kvh * HD + (w - 2) * 32 + lrow) * MROWS + bS + (lane & 3) * 8;
        g1 = g0 + (size_t)16 * MROWS;
        gstep = 32;
    }

    auto stage = [&](int sb) {
        if (w < 2) {
            gld16(g0, &Ks[sb][w][0][0]);
            gld16(g1, &Ks[sb][w][16][0]);
        } else {
            gld16(g0, &Vs[sb][(w - 2) * 32][0]);
            gld16(g1, &Vs[sb][(w - 2) * 32 + 16][0]);
        }
        g0 += gstep; g1 += gstep;
    };

    stage(0);
    stage(1);
    int cur = 0, nx2 = 2;
    for (int kt = 0; kt < nh32; kt++) {
        const int kbase = kt * 32;
        const bool dual = (kt < np32);        // wave-uniform
        // own stage(kt) landed (kt+1 still in flight); tail iterations drain
        if (kt + 1 < nh32) { __asm__ volatile("s_waitcnt vmcnt(2)" ::: "memory"); }
        else               { __asm__ volatile("s_waitcnt vmcnt(0)" ::: "memory"); }
        __builtin_amdgcn_s_barrier();         // all waves' stage(kt) visible
        __asm__ volatile("" ::: "memory");
        if (kt + 2 < nh32) stage(nx2);        // overwrites (kt-1)%3: safe post-barrier

        // S^T via swapped operands: lane holds S[qb+col][kbase+j*16+quad*4+r]
        f32x4 sH[2], sL[2];
        #pragma unroll
        for (int j = 0; j < 2; j++) { sH[j] = (f32x4){0.f,0.f,0.f,0.f}; sL[j] = (f32x4){0.f,0.f,0.f,0.f}; }
        __builtin_amdgcn_s_setprio(1);
        #pragma unroll
        for (int j = 0; j < 2; j++) {
            bf16x8 bk0 = *(const bf16x8*)&Ks[cur][0][j*16 + col][swz];
            bf16x8 bk1 = *(const bf16x8*)&Ks[cur][1][j*16 + col][swz];
            sH[j] = mfma32(bk0, aqH0, sH[j]);
            sH[j] = mfma32(bk1, aqH1, sH[j]);
            if (dual) {
                sL[j] = mfma32(bk0, aqL0, sL[j]);
                sL[j] = mfma32(bk1, aqL1, sL[j]);
            }
        }
        __builtin_amdgcn_s_setprio(0);

        // diagonal masking: k = kbase + j*16 + quad*4 + r vs q = qb + col
        if (kt >= nh32 - 2) {
            #pragma unroll
            for (int j = 0; j < 2; j++)
                #pragma unroll
                for (int r = 0; r < 4; r++)
                    if (kbase + j*16 + quad*4 + r > qbH + col) sH[j][r] = -1e30f;
        }
        if (dual && kt >= np32 - 2) {
            #pragma unroll
            for (int j = 0; j < 2; j++)
                #pragma unroll
                for (int r = 0; r < 4; r++)
                    if (kbase + j*16 + quad*4 + r > qbL + col) sL[j][r] = -1e30f;
        }

        // P fragments fully in-register (bf16-rounded exactly as before)
        s16x4 paH[2], paL[2];
        #pragma unroll
        for (int j = 0; j < 2; j++) {
            bf16x4 tb;
            #pragma unroll
            for (int r = 0; r < 4; r++) tb[r] = (__bf16)__builtin_amdgcn_exp2f(sH[j][r]);
            paH[j] = __builtin_bit_cast(s16x4, tb);
            lsumH = mfma16(paH[j], ones4, lsumH);   // rowsum, old layout preserved
        }
        if (dual) {
            #pragma unroll
            for (int j = 0; j < 2; j++) {
                bf16x4 tb;
                #pragma unroll
                for (int r = 0; r < 4; r++) tb[r] = (__bf16)__builtin_amdgcn_exp2f(sL[j][r]);
                paL[j] = __builtin_bit_cast(s16x4, tb);
                lsumL = mfma16(paL[j], ones4, lsumL);
            }
        }

        // PV: one b128 per dn yields both j fragments (V staged k-permuted)
        __builtin_amdgcn_s_setprio(1);
        #pragma unroll
        for (int dn = 0; dn < 4; dn++) {
            s16x8 bvv = *(const s16x8*)&Vs[cur][dn*16 + col][quad*8];
            s16x4 bv0 = __builtin_shufflevector(bvv, bvv, 0, 1, 2, 3);
            s16x4 bv1 = __builtin_shufflevector(bvv, bvv, 4, 5, 6, 7);
            oH[dn] = mfma16(paH[0], bv0, oH[dn]);
            oH[dn] = mfma16(paH[1], bv1, oH[dn]);
            if (dual) {
                oL[dn] = mfma16(paL[0], bv0, oL[dn]);
                oL[dn] = mfma16(paL[1], bv1, oL[dn]);
            }
        }
        __builtin_amdgcn_s_setprio(0);

        cur = (cur == 2) ? 0 : cur + 1;
        nx2 = (nx2 == 2) ? 0 : nx2 + 1;
    }

    #pragma unroll
    for (int r = 0; r < 4; r++) {
        float invL = 1.0f / lsumL[r];
        float invH = 1.0f / lsumH[r];
        __bf16* opL = O + (size_t)(b * SEQ + qbL + quad*4 + r) * HIDDEN + head * HD;
        __bf16* opH = O + (size_t)(b * SEQ + qbH + quad*4 + r) * HIDDEN + head * HD;
        #pragma unroll
        for (int dn = 0; dn < 4; dn++) {
            opL[dn*16 + col] = (__bf16)(oL[dn][r] * invL);
            opH[dn*16 + col] = (__bf16)(oH[dn][r] * invH);
        }
    }
}

// ---------------- launch ----------------
extern "C" void kernel_launch(void* const* d_in, const int* in_sizes, int n_in,
                              void* d_out, int out_size, void* d_ws, size_t ws_size,
                              hipStream_t stream) {
    const float* x  = (const float*)d_in[0];
    const float* Wq = (const float*)d_in[1];
    const float* Wk = (const float*)d_in[2];
    const float* Wv = (const float*)d_in[3];
    const float* Wo = (const float*)d_in[4];
    float* out = (float*)d_out;

    __bf16* p    = (__bf16*)d_ws;
    __bf16* xb   = p; p += (size_t)MROWS * HIDDEN;
    __bf16* wqkv = p; p += (size_t)QKVN * HIDDEN;
    __bf16* wob  = p; p += (size_t)HIDDEN * HIDDEN;
    __bf16* qkv  = p; p += (size_t)MROWS * QKVN;
    __bf16* vt   = p; p += (size_t)KVDIM * MROWS;
    __bf16* aob  = xb;   // alias: x not needed post-projection

    const float qscale = 0.125f * 1.4426950408889634f;
    cast_all<<<18432, 256, 0, stream>>>(x, Wq, Wk, Wv, Wo, xb, wqkv, wob, qscale);

    dim3 blk(256);
    gemm128<__bf16><<<dim3(QKVN/128, MROWS/128), blk, 0, stream>>>(xb, wqkv, qkv, MROWS, QKVN, HIDDEN);
    transpose_v<<<dim3(KVDIM/64, MROWS/64), blk, 0, stream>>>(qkv, vt);
    flash_attn<<<BATCH * NHEADS * (SEQ/128), blk, 0, stream>>>(qkv, vt, aob);
    gemm128<float><<<dim3(HIDDEN/128, MROWS/128), blk, 0, stream>>>(aob, wob, out, MROWS, HIDDEN, HIDDEN);
}

// Round 4
// 283.872 us; speedup vs baseline: 1.1804x; 1.1014x over previous
//
#include <hip/hip_runtime.h>

#define HIDDEN 2048
#define NHEADS 32
#define NKV 8
#define HD 64
#define BATCH 2
#define SEQ 2048
#define MROWS (BATCH*SEQ)        // 4096
#define KVDIM (NKV*HD)           // 512
#define QKVN (HIDDEN + 2*KVDIM)  // 3072

typedef __bf16 bf16x8 __attribute__((ext_vector_type(8)));
typedef __bf16 bf16x4 __attribute__((ext_vector_type(4)));
typedef float f32x4 __attribute__((ext_vector_type(4)));

__device__ inline f32x4 mfma32(bf16x8 a, bf16x8 b, f32x4 c) {
    return __builtin_amdgcn_mfma_f32_16x16x32_bf16(a, b, c, 0, 0, 0);
}

// async global->LDS, 16B per lane; lds base must be wave-uniform (HW: base + lane*16)
__device__ inline void gld16(const __bf16* g, __bf16* l) {
    __builtin_amdgcn_global_load_lds((const __attribute__((address_space(1))) void*)g,
                                     (__attribute__((address_space(3))) void*)l, 16, 0, 0);
}

// ---------------- fused cast fp32 -> bf16 for all 5 tensors ----------------
__global__ __launch_bounds__(256) void cast_all(const float* __restrict__ x,
                                                const float* __restrict__ wq,
                                                const float* __restrict__ wk,
                                                const float* __restrict__ wv,
                                                const float* __restrict__ wo,
                                                __bf16* __restrict__ xb,
                                                __bf16* __restrict__ wqkv,
                                                __bf16* __restrict__ wob,
                                                float qscale) {
    int blk = blockIdx.x;
    const float* src; __bf16* dst; float sc = 1.0f; size_t off;
    if (blk < 8192)        { src = x;  dst = xb;   off = (size_t)blk * 1024; }
    else if (blk < 12288)  { src = wq; dst = wqkv; off = (size_t)(blk - 8192) * 1024; sc = qscale; }
    else if (blk < 13312)  { src = wk; dst = wqkv + (size_t)HIDDEN * HIDDEN; off = (size_t)(blk - 12288) * 1024; }
    else if (blk < 14336)  { src = wv; dst = wqkv + (size_t)(HIDDEN + KVDIM) * HIDDEN; off = (size_t)(blk - 13312) * 1024; }
    else                   { src = wo; dst = wob;  off = (size_t)(blk - 14336) * 1024; }
    size_t i4 = off + (size_t)threadIdx.x * 4;
    float4 f = *(const float4*)(src + i4);
    dst[i4 + 0] = (__bf16)(f.x * sc);
    dst[i4 + 1] = (__bf16)(f.y * sc);
    dst[i4 + 2] = (__bf16)(f.z * sc);
    dst[i4 + 3] = (__bf16)(f.w * sc);
}

__device__ inline void store_val(__bf16* C, size_t idx, float v) { C[idx] = (__bf16)v; }
__device__ inline void store_val(float* C, size_t idx, float v) { C[idx] = v; }

// ---------------- GEMM: C = A(M,K) @ B(N,K)^T; double-buffered LDS, BK=32 -----
template <typename OutT>
__global__ __launch_bounds__(256) void gemm128(const __bf16* __restrict__ A,
                                               const __bf16* __restrict__ B,
                                               OutT* __restrict__ C,
                                               int M, int N, int K) {
    __shared__ __bf16 As[2][128][32];
    __shared__ __bf16 Bs[2][128][32];
    const int tid  = threadIdx.x;
    const int lane = tid & 63;
    const int w    = tid >> 6;
    const int col  = lane & 15;
    const int quad = lane >> 4;
    const int m0 = blockIdx.y * 128;
    const int n0 = blockIdx.x * 128;
    const int wm = (w >> 1) * 64;
    const int wn = (w & 1) * 64;

    f32x4 acc[4][4];
    #pragma unroll
    for (int i = 0; i < 4; i++)
        #pragma unroll
        for (int j = 0; j < 4; j++) acc[i][j] = (f32x4){0.f,0.f,0.f,0.f};

    const int lrow = lane >> 2;        // 0..15
    const int lcol = (lane & 3) * 8;   // 0,8,16,24

    auto stage = [&](int k0, int buf) {
        #pragma unroll
        for (int c = 0; c < 4; c++) {
            int chunk = w * 4 + c;
            if (chunk < 8) {
                const __bf16* g = A + (size_t)(m0 + chunk*16 + lrow) * K + k0 + lcol;
                gld16(g, &As[buf][chunk*16][0]);
            } else {
                int bc = chunk - 8;
                const __bf16* g = B + (size_t)(n0 + bc*16 + lrow) * K + k0 + lcol;
                gld16(g, &Bs[buf][bc*16][0]);
            }
        }
    };

    const int nk = K / 32;
    stage(0, 0);
    for (int ki = 0; ki < nk; ki++) {
        const int buf = ki & 1;
        __syncthreads();                      // drains stage(ki) DMA; frees buf^1
        if (ki + 1 < nk) stage((ki + 1) * 32, buf ^ 1);   // overlaps compute below

        bf16x8 af[4], bfr[4];
        #pragma unroll
        for (int i = 0; i < 4; i++) af[i]  = *(const bf16x8*)&As[buf][wm + i*16 + col][quad*8];
        #pragma unroll
        for (int j = 0; j < 4; j++) bfr[j] = *(const bf16x8*)&Bs[buf][wn + j*16 + col][quad*8];
        #pragma unroll
        for (int i = 0; i < 4; i++)
            #pragma unroll
            for (int j = 0; j < 4; j++)
                acc[i][j] = __builtin_amdgcn_mfma_f32_16x16x32_bf16(af[i], bfr[j], acc[i][j], 0, 0, 0);
    }

    #pragma unroll
    for (int i = 0; i < 4; i++) {
        #pragma unroll
        for (int r = 0; r < 4; r++) {
            int mrow = m0 + wm + i*16 + quad*4 + r;
            size_t base = (size_t)mrow * N + n0 + wn;
            #pragma unroll
            for (int j = 0; j < 4; j++)
                store_val(C, base + j*16 + col, acc[i][j][r]);
        }
    }
}

// ---------------- V transpose with k-order permutation -----------------------
// VT[d][32-block B][o] = V[s = 32B + sigma(o)][d], sigma: o=Q*8+e -> (e>>2)*16+Q*4+(e&3).
// A ds_read_b128 at [d][quad*8] in flash yields the B-fragment of a K=32 MFMA
// whose A operand is concat(pa[0], pa[1]) with logical k = (e>>2)*16+quad*4+(e&3)
// -- i.e. the swapped-QK^T S layout feeds PV directly, zero cross-lane.
__global__ __launch_bounds__(256) void transpose_v(const __bf16* __restrict__ QKV,
                                                   __bf16* __restrict__ VT) {
    __shared__ __bf16 tile[64][72];
    const int r0 = blockIdx.x * 64;
    const int s0 = blockIdx.y * 64;
    const int t  = threadIdx.x;
    #pragma unroll
    for (int cc = 0; cc < 2; cc++) {
        int c = t + cc * 256;
        int i = c >> 3;
        int j8 = (c & 7) * 8;
        bf16x8 v = *(const bf16x8*)(QKV + (size_t)(s0 + i) * QKVN + (HIDDEN + KVDIM) + r0 + j8);
        *(bf16x8*)&tile[i][j8] = v;
    }
    __syncthreads();
    #pragma unroll
    for (int cc = 0; cc < 2; cc++) {
        int c = t + cc * 256;
        int d = c >> 3;
        int m = c & 7;                 // output 8-elem chunk within 64 s-positions
        bf16x8 vv;
        #pragma unroll
        for (int tt = 0; tt < 8; tt++) {
            // out offset o=8m+tt -> s_local = (m>>2)*32 + (tt>>2)*16 + (m&3)*4 + (tt&3)
            int sl = (m >> 2) * 32 + (tt >> 2) * 16 + (m & 3) * 4 + (tt & 3);
            vv[tt] = tile[sl][d];
        }
        *(bf16x8*)(VT + (size_t)(r0 + d) * MROWS + s0 + m * 8) = vv;
    }
}

// ---------------- flash attention: single-tile blocks, all-K=32, 3-buf K/V ----
// One block per (batch, head, 64-row q-tile): 2048 blocks, dispatched
// LONGEST-FIRST (t = 31 - (bid>>6)) so the 64-iter blocks start immediately and
// short blocks backfill the tail. LDS 24 KB -> 6 blocks/CU resident (24 waves,
// vs 16 before) with 512 queued blocks to keep CUs fed -- attacks the measured
// 21% occupancy / 52% VALUBusy latency-chain starvation.
// QK^T swapped (mfma(K,Q)): lane holds S[q=qb+col][k=kbase+j*16+quad*4+r].
// P = exp2(S) packed in-register to ONE bf16x8 (k = (e>>2)*16+quad*4+(e&3)) and
// fed to K=32 MFMAs for both PV (V staged sigma-permuted, see transpose_v) and
// the ones-rowsum: 9 MFMA/tile vs 14 with the former K=16 pairs (16x16x16
// issues at the same rate as 16x16x32 but half the FLOPs).
// Ks/Vs triple-buffered; raw s_barrier + counted s_waitcnt vmcnt(2).
// Q pre-scaled by (1/8)*log2(e); fixed-max exp2 softmax.
__global__ __launch_bounds__(256) void flash_attn(const __bf16* __restrict__ QKV,
                                                  const __bf16* __restrict__ VT,
                                                  __bf16* __restrict__ O) {
    const int bid  = blockIdx.x;
    const int t    = 31 - (bid >> 6);         // q-tile index, longest first
    const int head = (bid >> 1) & 31;
    const int b    = bid & 1;
    const int kvh  = head >> 2;
    const int tid  = threadIdx.x;
    const int lane = tid & 63;
    const int w    = tid >> 6;
    const int col  = lane & 15;
    const int quad = lane >> 4;

    const int qb   = t * 64 + w * 16;         // this wave's 16 q-rows
    const int n32  = (t + 1) * 2;             // k-tiles (32-granular), >=2

    __shared__ __bf16 Ks[3][2][32][32];  // [buf][d-half][kpos][d32]  12 KB
    __shared__ __bf16 Vs[3][64][32];     // [buf][d][k-perm o]        12 KB

    const size_t qO = (size_t)(b * SEQ + qb + col) * QKVN + head * HD;
    bf16x8 aq0 = *(const bf16x8*)(QKV + qO + quad * 8);
    bf16x8 aq1 = *(const bf16x8*)(QKV + qO + 32 + quad * 8);

    bf16x8 ones8;
    #pragma unroll
    for (int j = 0; j < 8; j++) ones8[j] = (__bf16)1.0f;

    f32x4 o[4];
    #pragma unroll
    for (int dn = 0; dn < 4; dn++) o[dn] = (f32x4){0.f,0.f,0.f,0.f};
    f32x4 lsum = (f32x4){0.f,0.f,0.f,0.f};

    const int lrow = lane >> 2;                        // 0..15 (staging row)
    const int srcc8 = (((lane & 3) ^ (lrow & 3)) * 8); // swizzled source chunk (K)
    const int swz   = (quad ^ (col & 3)) * 8;          // swizzled K read chunk
    const size_t bS = (size_t)b * SEQ;

    // Hoisted per-lane stage pointers (advance by constant stride per tile).
    // Waves 0,1 stage K d-halves 0,1; waves 2,3 stage V d 0-31 / 32-63.
    const __bf16 *g0, *g1;
    size_t gstep;
    if (w < 2) {
        g0 = QKV + (bS + lrow) * QKVN + HIDDEN + kvh * HD + w * 32 + srcc8;
        g1 = g0 + (size_t)16 * QKVN;
        gstep = (size_t)32 * QKVN;
    } else {
        g0 = VT + (size_t)(kvh * HD + (w - 2) * 32 + lrow) * MROWS + bS + (lane & 3) * 8;
        g1 = g0 + (size_t)16 * MROWS;
        gstep = 32;
    }

    auto stage = [&](int sb) {
        if (w < 2) {
            gld16(g0, &Ks[sb][w][0][0]);
            gld16(g1, &Ks[sb][w][16][0]);
        } else {
            gld16(g0, &Vs[sb][(w - 2) * 32][0]);
            gld16(g1, &Vs[sb][(w - 2) * 32 + 16][0]);
        }
        g0 += gstep; g1 += gstep;
    };

    stage(0);
    stage(1);
    int cur = 0, nx2 = 2;
    for (int kt = 0; kt < n32; kt++) {
        const int kbase = kt * 32;
        // own stage(kt) landed (kt+1 still in flight); tail iterations drain
        if (kt + 1 < n32) { __asm__ volatile("s_waitcnt vmcnt(2)" ::: "memory"); }
        else              { __asm__ volatile("s_waitcnt vmcnt(0)" ::: "memory"); }
        __builtin_amdgcn_s_barrier();         // all waves' stage(kt) visible
        __asm__ volatile("" ::: "memory");
        if (kt + 2 < n32) stage(nx2);         // overwrites (kt-1)%3: safe post-barrier

        // S^T via swapped operands: lane holds S[qb+col][kbase+j*16+quad*4+r]
        f32x4 s[2];
        s[0] = (f32x4){0.f,0.f,0.f,0.f};
        s[1] = (f32x4){0.f,0.f,0.f,0.f};
        __builtin_amdgcn_s_setprio(1);
        #pragma unroll
        for (int j = 0; j < 2; j++) {
            bf16x8 bk0 = *(const bf16x8*)&Ks[cur][0][j*16 + col][swz];
            bf16x8 bk1 = *(const bf16x8*)&Ks[cur][1][j*16 + col][swz];
            s[j] = mfma32(bk0, aq0, s[j]);
            s[j] = mfma32(bk1, aq1, s[j]);
        }
        __builtin_amdgcn_s_setprio(0);

        // diagonal masking: k = kbase + j*16 + quad*4 + r vs q = qb + col
        if (kt >= n32 - 2) {
            #pragma unroll
            for (int j = 0; j < 2; j++)
                #pragma unroll
                for (int r = 0; r < 4; r++)
                    if (kbase + j*16 + quad*4 + r > qb + col) s[j][r] = -1e30f;
        }

        // P fully in-register as one K=32 A-fragment: elem e=j*4+r at hw k=quad*8+e
        bf16x8 pa;
        #pragma unroll
        for (int j = 0; j < 2; j++)
            #pragma unroll
            for (int r = 0; r < 4; r++)
                pa[j*4 + r] = (__bf16)__builtin_amdgcn_exp2f(s[j][r]);

        __builtin_amdgcn_s_setprio(1);
        lsum = mfma32(pa, ones8, lsum);       // rowsum, layout matches epilogue
        #pragma unroll
        for (int dn = 0; dn < 4; dn++) {
            bf16x8 bv = *(const bf16x8*)&Vs[cur][dn*16 + col][quad*8];
            o[dn] = mfma32(pa, bv, o[dn]);    // V sigma-permuted: one MFMA per dn
        }
        __builtin_amdgcn_s_setprio(0);

        cur = (cur == 2) ? 0 : cur + 1;
        nx2 = (nx2 == 2) ? 0 : nx2 + 1;
    }

    #pragma unroll
    for (int r = 0; r < 4; r++) {
        float inv = 1.0f / lsum[r];
        __bf16* op = O + (size_t)(b * SEQ + qb + quad*4 + r) * HIDDEN + head * HD;
        #pragma unroll
        for (int dn = 0; dn < 4; dn++)
            op[dn*16 + col] = (__bf16)(o[dn][r] * inv);
    }
}

// ---------------- launch ----------------
extern "C" void kernel_launch(void* const* d_in, const int* in_sizes, int n_in,
                              void* d_out, int out_size, void* d_ws, size_t ws_size,
                              hipStream_t stream) {
    const float* x  = (const float*)d_in[0];
    const float* Wq = (const float*)d_in[1];
    const float* Wk = (const float*)d_in[2];
    const float* Wv = (const float*)d_in[3];
    const float* Wo = (const float*)d_in[4];
    float* out = (float*)d_out;

    __bf16* p    = (__bf16*)d_ws;
    __bf16* xb   = p; p += (size_t)MROWS * HIDDEN;
    __bf16* wqkv = p; p += (size_t)QKVN * HIDDEN;
    __bf16* wob  = p; p += (size_t)HIDDEN * HIDDEN;
    __bf16* qkv  = p; p += (size_t)MROWS * QKVN;
    __bf16* vt   = p; p += (size_t)KVDIM * MROWS;
    __bf16* aob  = xb;   // alias: x not needed post-projection

    const float qscale = 0.125f * 1.4426950408889634f;
    cast_all<<<18432, 256, 0, stream>>>(x, Wq, Wk, Wv, Wo, xb, wqkv, wob, qscale);

    dim3 blk(256);
    gemm128<__bf16><<<dim3(QKVN/128, MROWS/128), blk, 0, stream>>>(xb, wqkv, qkv, MROWS, QKVN, HIDDEN);
    transpose_v<<<dim3(KVDIM/64, MROWS/64), blk, 0, stream>>>(qkv, vt);
    flash_attn<<<BATCH * NHEADS * (SEQ/64), blk, 0, stream>>>(qkv, vt, aob);
    gemm128<float><<<dim3(HIDDEN/128, MROWS/128), blk, 0, stream>>>(aob, wob, out, MROWS, HIDDEN, HIDDEN);
}

// Round 6
// 280.008 us; speedup vs baseline: 1.1967x; 1.0138x over previous
//
#include <hip/hip_runtime.h>

#define HIDDEN 2048
#define NHEADS 32
#define NKV 8
#define HD 64
#define BATCH 2
#define SEQ 2048
#define MROWS (BATCH*SEQ)        // 4096
#define KVDIM (NKV*HD)           // 512
#define QKVN (HIDDEN + 2*KVDIM)  // 3072

typedef __bf16 bf16x8 __attribute__((ext_vector_type(8)));
typedef __bf16 bf16x4 __attribute__((ext_vector_type(4)));
typedef float f32x4 __attribute__((ext_vector_type(4)));

__device__ inline f32x4 mfma32(bf16x8 a, bf16x8 b, f32x4 c) {
    return __builtin_amdgcn_mfma_f32_16x16x32_bf16(a, b, c, 0, 0, 0);
}

// async global->LDS, 16B per lane; lds base must be wave-uniform (HW: base + lane*16)
__device__ inline void gld16(const __bf16* g, __bf16* l) {
    __builtin_amdgcn_global_load_lds((const __attribute__((address_space(1))) void*)g,
                                     (__attribute__((address_space(3))) void*)l, 16, 0, 0);
}

// ---------------- fused cast fp32 -> bf16 for all 5 tensors ----------------
__global__ __launch_bounds__(256) void cast_all(const float* __restrict__ x,
                                                const float* __restrict__ wq,
                                                const float* __restrict__ wk,
                                                const float* __restrict__ wv,
                                                const float* __restrict__ wo,
                                                __bf16* __restrict__ xb,
                                                __bf16* __restrict__ wqkv,
                                                __bf16* __restrict__ wob,
                                                float qscale) {
    int blk = blockIdx.x;
    const float* src; __bf16* dst; float sc = 1.0f; size_t off;
    if (blk < 8192)        { src = x;  dst = xb;   off = (size_t)blk * 1024; }
    else if (blk < 12288)  { src = wq; dst = wqkv; off = (size_t)(blk - 8192) * 1024; sc = qscale; }
    else if (blk < 13312)  { src = wk; dst = wqkv + (size_t)HIDDEN * HIDDEN; off = (size_t)(blk - 12288) * 1024; }
    else if (blk < 14336)  { src = wv; dst = wqkv + (size_t)(HIDDEN + KVDIM) * HIDDEN; off = (size_t)(blk - 13312) * 1024; }
    else                   { src = wo; dst = wob;  off = (size_t)(blk - 14336) * 1024; }
    size_t i4 = off + (size_t)threadIdx.x * 4;
    float4 f = *(const float4*)(src + i4);
    dst[i4 + 0] = (__bf16)(f.x * sc);
    dst[i4 + 1] = (__bf16)(f.y * sc);
    dst[i4 + 2] = (__bf16)(f.z * sc);
    dst[i4 + 3] = (__bf16)(f.w * sc);
}

__device__ inline void store_val(__bf16* C, size_t idx, float v) { C[idx] = (__bf16)v; }
__device__ inline void store_val(float* C, size_t idx, float v) { C[idx] = v; }

// ---------------- GEMM (gemm2): C = A(M,K) @ B(N,K)^T; 128^2, BK=32 ----------
template <typename OutT>
__global__ __launch_bounds__(256) void gemm128(const __bf16* __restrict__ A,
                                               const __bf16* __restrict__ B,
                                               OutT* __restrict__ C,
                                               int M, int N, int K) {
    __shared__ __bf16 As[2][128][32];
    __shared__ __bf16 Bs[2][128][32];
    const int tid  = threadIdx.x;
    const int lane = tid & 63;
    const int w    = tid >> 6;
    const int col  = lane & 15;
    const int quad = lane >> 4;
    const int m0 = blockIdx.y * 128;
    const int n0 = blockIdx.x * 128;
    const int wm = (w >> 1) * 64;
    const int wn = (w & 1) * 64;

    f32x4 acc[4][4];
    #pragma unroll
    for (int i = 0; i < 4; i++)
        #pragma unroll
        for (int j = 0; j < 4; j++) acc[i][j] = (f32x4){0.f,0.f,0.f,0.f};

    const int lrow = lane >> 2;        // 0..15
    const int lcol = (lane & 3) * 8;   // 0,8,16,24

    auto stage = [&](int k0, int buf) {
        #pragma unroll
        for (int c = 0; c < 4; c++) {
            int chunk = w * 4 + c;
            if (chunk < 8) {
                const __bf16* g = A + (size_t)(m0 + chunk*16 + lrow) * K + k0 + lcol;
                gld16(g, &As[buf][chunk*16][0]);
            } else {
                int bc = chunk - 8;
                const __bf16* g = B + (size_t)(n0 + bc*16 + lrow) * K + k0 + lcol;
                gld16(g, &Bs[buf][bc*16][0]);
            }
        }
    };

    const int nk = K / 32;
    stage(0, 0);
    for (int ki = 0; ki < nk; ki++) {
        const int buf = ki & 1;
        __syncthreads();                      // drains stage(ki) DMA; frees buf^1
        if (ki + 1 < nk) stage((ki + 1) * 32, buf ^ 1);   // overlaps compute below

        bf16x8 af[4], bfr[4];
        #pragma unroll
        for (int i = 0; i < 4; i++) af[i]  = *(const bf16x8*)&As[buf][wm + i*16 + col][quad*8];
        #pragma unroll
        for (int j = 0; j < 4; j++) bfr[j] = *(const bf16x8*)&Bs[buf][wn + j*16 + col][quad*8];
        #pragma unroll
        for (int i = 0; i < 4; i++)
            #pragma unroll
            for (int j = 0; j < 4; j++)
                acc[i][j] = __builtin_amdgcn_mfma_f32_16x16x32_bf16(af[i], bfr[j], acc[i][j], 0, 0, 0);
    }

    #pragma unroll
    for (int i = 0; i < 4; i++) {
        #pragma unroll
        for (int r = 0; r < 4; r++) {
            int mrow = m0 + wm + i*16 + quad*4 + r;
            size_t base = (size_t)mrow * N + n0 + wn;
            #pragma unroll
            for (int j = 0; j < 4; j++)
                store_val(C, base + j*16 + col, acc[i][j][r]);
        }
    }
}

// ---------------- GEMM (gemm1): 256^2 tile, BK=64, 8-wave 8-phase schedule ----
// Plain-HIP port of the validated 8-phase template (T3+T4 counted vmcnt, T2
// bank swizzle, T5 setprio). 512 thr = 2x4 waves, 128x64 C per wave, LDS 128KB
// (2 bufs x [256][64] for A and B). Per K-tile: 4 quadrant-phases, each
// {ds_read subtile | issue 1-2 prefetch half-tiles} -> barrier -> lgkmcnt(0) ->
// 16 MFMA -> barrier. ONE counted s_waitcnt vmcnt(6) gate per K-tile (never 0
// in steady state): 3 half-tiles (6 loads) stay in flight across barriers.
// Issue ledger (derived, race-checked against read windows):
//   q0: A-h1(t+1) [buf^1: idle this tile]      q2: B-h0(t+2) [B reads drained by bar2(q1)]
//   q3: A-h0(t+2) [A reads drained by bar2(q2)] + B-h1(t+2)
// Swizzle (both-sides, rule #21): LDS chunk c at row r holds global chunk
// c ^ ((r>>1)&7); staged via pre-swizzled per-lane global source (dest linear,
// DMA-compatible), read back with the same XOR. Spreads each wave b128 read
// over all 32 banks (2 lanes/bank = free; linear layout was 16-way).
// K accumulation order identical to gemm128 -> bit-identical C.
__global__ __launch_bounds__(512, 2) void gemm256(const __bf16* __restrict__ A,
                                                  const __bf16* __restrict__ B,
                                                  __bf16* __restrict__ C,
                                                  int M, int N, int K) {
    __shared__ __bf16 As[2][256][64];
    __shared__ __bf16 Bs[2][256][64];
    const int tid  = threadIdx.x;
    const int lane = tid & 63;
    const int w    = tid >> 6;       // 0..7
    const int wr   = w >> 2;         // 0..1 (M)
    const int wc   = w & 3;          // 0..3 (N)
    const int col  = lane & 15;
    const int quad = lane >> 4;
    const int m0 = blockIdx.y * 256;
    const int n0 = blockIdx.x * 256;
    const int nk = K >> 6;

    f32x4 acc[8][4];
    #pragma unroll
    for (int i = 0; i < 8; i++)
        #pragma unroll
        for (int j = 0; j < 4; j++) acc[i][j] = (f32x4){0.f,0.f,0.f,0.f};

    bf16x8 afr[4][2];   // current A m-half fragments [ii][kk]
    bf16x8 bfr[4][2];   // all 4 B n-fragments resident [j16][kk]

    // per-lane pre-swizzled staging sources: issue i stages rows w*16+i*8+(lane>>3),
    // source chunk (lane&7) ^ ((row>>1)&7) = (lane&7) ^ (i*4 + quad)
    const int r8 = lane >> 3, c8 = lane & 7;
    const __bf16* pA0 = A + (size_t)(m0 + w*16 +     r8) * K + ((c8 ^ quad) * 8);
    const __bf16* pA1 = A + (size_t)(m0 + w*16 + 8 + r8) * K + ((c8 ^ (4 + quad)) * 8);
    const __bf16* pB0 = B + (size_t)(n0 + w*16 +     r8) * K + ((c8 ^ quad) * 8);
    const __bf16* pB1 = B + (size_t)(n0 + w*16 + 8 + r8) * K + ((c8 ^ (4 + quad)) * 8);
    const int ldsrow = w * 16;   // wave-uniform dest row base
    const int rsw = col >> 1;    // read-side swizzle term

#define G2_BAR()   { __asm__ volatile("" ::: "memory"); __builtin_amdgcn_s_barrier(); __asm__ volatile("" ::: "memory"); }
#define G2_LGKM0() { __asm__ volatile("s_waitcnt lgkmcnt(0)" ::: "memory"); __builtin_amdgcn_sched_barrier(0); }
#define G2_ISSUE(tile, sel) do {                                                             \
    int _t = (tile);                                                                         \
    if (_t < nk) {                                                                           \
        int _b = _t & 1; size_t _ko = (size_t)_t * 64;                                       \
        if      ((sel) == 0) { gld16(pA0 + _ko, &As[_b][ldsrow][0]);                         \
                               gld16(pA1 + _ko, &As[_b][ldsrow + 8][0]); }                   \
        else if ((sel) == 1) { gld16(pA0 + (size_t)128*K + _ko, &As[_b][128 + ldsrow][0]);   \
                               gld16(pA1 + (size_t)128*K + _ko, &As[_b][128 + ldsrow + 8][0]); } \
        else if ((sel) == 2) { gld16(pB0 + _ko, &Bs[_b][ldsrow][0]);                         \
                               gld16(pB1 + _ko, &Bs[_b][ldsrow + 8][0]); }                   \
        else                 { gld16(pB0 + (size_t)128*K + _ko, &Bs[_b][128 + ldsrow][0]);   \
                               gld16(pB1 + (size_t)128*K + _ko, &Bs[_b][128 + ldsrow + 8][0]); } \
    } } while (0)
#define G2_LDA(mh) {                                                                         \
    _Pragma("unroll")                                                                        \
    for (int ii = 0; ii < 4; ii++) {                                                         \
        const __bf16* _rp = &As[buf][wr*128 + ((mh)*4 + ii)*16 + col][0];                    \
        _Pragma("unroll")                                                                    \
        for (int kk = 0; kk < 2; kk++)                                                       \
            afr[ii][kk] = *(const bf16x8*)(_rp + (((kk*4 + quad) ^ rsw) * 8));               \
    } }
#define G2_LDB(nh) {                                                                         \
    _Pragma("unroll")                                                                        \
    for (int jj = 0; jj < 2; jj++) {                                                         \
        const __bf16* _rp = &Bs[buf][wc*64 + ((nh)*2 + jj)*16 + col][0];                     \
        _Pragma("unroll")                                                                    \
        for (int kk = 0; kk < 2; kk++)                                                       \
            bfr[(nh)*2 + jj][kk] = *(const bf16x8*)(_rp + (((kk*4 + quad) ^ rsw) * 8));      \
    } }
#define G2_MM(mh, nh) {                                                                      \
    __builtin_amdgcn_s_setprio(1);                                                           \
    _Pragma("unroll")                                                                        \
    for (int ii = 0; ii < 4; ii++)                                                           \
        _Pragma("unroll")                                                                    \
        for (int jj = 0; jj < 2; jj++)                                                       \
            _Pragma("unroll")                                                                \
            for (int kk = 0; kk < 2; kk++)                                                   \
                acc[(mh)*4 + ii][(nh)*2 + jj] =                                              \
                    mfma32(afr[ii][kk], bfr[(nh)*2 + jj][kk], acc[(mh)*4 + ii][(nh)*2 + jj]); \
    __builtin_amdgcn_s_setprio(0); }

    // prologue: tile0 fully + tile1 {A0,B0,B1}; A1(1) comes from (t=0,q0)
    G2_ISSUE(0, 0); G2_ISSUE(0, 1); G2_ISSUE(0, 2); G2_ISSUE(0, 3);
    G2_ISSUE(1, 0); G2_ISSUE(1, 2); G2_ISSUE(1, 3);
    __asm__ volatile("s_waitcnt vmcnt(6)" ::: "memory");   // tile0 landed
    G2_BAR();

    for (int t = 0; t < nk; ++t) {
        const int buf = t & 1;
        // q0: read A-mh0 + all B; prefetch A-h1(t+1) into idle buf^1
        G2_LDA(0); G2_LDB(0);
        G2_ISSUE(t + 1, 1);
        G2_BAR(); G2_LGKM0();
        G2_MM(0, 0);
        G2_BAR();
        // q1: read B-nh1
        G2_LDB(1);
        G2_BAR(); G2_LGKM0();
        G2_MM(0, 1);
        G2_BAR();
        // q2: read A-mh1; B reads of buf all drained -> prefetch B-h0(t+2)
        G2_LDA(1);
        G2_ISSUE(t + 2, 2);
        G2_BAR(); G2_LGKM0();
        G2_MM(1, 1);
        G2_BAR();
        // q3: no reads; A reads of buf drained -> prefetch A-h0(t+2), B-h1(t+2)
        G2_ISSUE(t + 2, 0);
        G2_ISSUE(t + 2, 3);
        G2_BAR(); G2_LGKM0();
        G2_MM(1, 0);
        // per-tile gate: tile t+1 landed, 3 half-tiles (6 loads) stay in flight
        if (t + 3 <= nk) { __asm__ volatile("s_waitcnt vmcnt(6)" ::: "memory"); }
        else             { __asm__ volatile("s_waitcnt vmcnt(0)" ::: "memory"); }
        G2_BAR();
    }

    #pragma unroll
    for (int i16 = 0; i16 < 8; i16++) {
        #pragma unroll
        for (int r = 0; r < 4; r++) {
            size_t base = (size_t)(m0 + wr*128 + i16*16 + quad*4 + r) * N + n0 + wc*64;
            #pragma unroll
            for (int j16 = 0; j16 < 4; j16++)
                C[base + j16*16 + col] = (__bf16)acc[i16][j16][r];
        }
    }
#undef G2_BAR
#undef G2_LGKM0
#undef G2_ISSUE
#undef G2_LDA
#undef G2_LDB
#undef G2_MM
}

// ---------------- V transpose with k-order permutation -----------------------
// VT[d][32-block B][o] = V[s = 32B + sigma(o)][d], sigma: o=Q*8+e -> (e>>2)*16+Q*4+(e&3).
// A ds_read_b128 at [d][quad*8] in flash yields the B-fragment of a K=32 MFMA
// whose A operand is the in-register P fragment -- zero cross-lane.
__global__ __launch_bounds__(256) void transpose_v(const __bf16* __restrict__ QKV,
                                                   __bf16* __restrict__ VT) {
    __shared__ __bf16 tile[64][72];
    const int r0 = blockIdx.x * 64;
    const int s0 = blockIdx.y * 64;
    const int t  = threadIdx.x;
    #pragma unroll
    for (int cc = 0; cc < 2; cc++) {
        int c = t + cc * 256;
        int i = c >> 3;
        int j8 = (c & 7) * 8;
        bf16x8 v = *(const bf16x8*)(QKV + (size_t)(s0 + i) * QKVN + (HIDDEN + KVDIM) + r0 + j8);
        *(bf16x8*)&tile[i][j8] = v;
    }
    __syncthreads();
    #pragma unroll
    for (int cc = 0; cc < 2; cc++) {
        int c = t + cc * 256;
        int d = c >> 3;
        int m = c & 7;                 // output 8-elem chunk within 64 s-positions
        bf16x8 vv;
        #pragma unroll
        for (int tt = 0; tt < 8; tt++) {
            // out offset o=8m+tt -> s_local = (m>>2)*32 + (tt>>2)*16 + (m&3)*4 + (tt&3)
            int sl = (m >> 2) * 32 + (tt >> 2) * 16 + (m & 3) * 4 + (tt & 3);
            vv[tt] = tile[sl][d];
        }
        *(bf16x8*)(VT + (size_t)(r0 + d) * MROWS + s0 + m * 8) = vv;
    }
}

// ---------------- flash attention: single-tile blocks, all-K=32, 3-buf K/V ----
// One block per (batch, head, 64-row q-tile): 2048 blocks, longest-first.
// QK^T swapped (mfma(K,Q)); P = exp2(S) packed in-register to ONE bf16x8 and
// fed to K=32 MFMAs for PV (V sigma-permuted) and the ones-rowsum.
// Ks/Vs triple-buffered; raw s_barrier + counted s_waitcnt vmcnt(2).
// Q pre-scaled by (1/8)*log2(e); fixed-max exp2 softmax.
__global__ __launch_bounds__(256) void flash_attn(const __bf16* __restrict__ QKV,
                                                  const __bf16* __restrict__ VT,
                                                  __bf16* __restrict__ O) {
    const int bid  = blockIdx.x;
    const int t    = 31 - (bid >> 6);         // q-tile index, longest first
    const int head = (bid >> 1) & 31;
    const int b    = bid & 1;
    const int kvh  = head >> 2;
    const int tid  = threadIdx.x;
    const int lane = tid & 63;
    const int w    = tid >> 6;
    const int col  = lane & 15;
    const int quad = lane >> 4;

    const int qb   = t * 64 + w * 16;         // this wave's 16 q-rows
    const int n32  = (t + 1) * 2;             // k-tiles (32-granular), >=2

    __shared__ __bf16 Ks[3][2][32][32];  // [buf][d-half][kpos][d32]  12 KB
    __shared__ __bf16 Vs[3][64][32];     // [buf][d][k-perm o]        12 KB

    const size_t qO = (size_t)(b * SEQ + qb + col) * QKVN + head * HD;
    bf16x8 aq0 = *(const bf16x8*)(QKV + qO + quad * 8);
    bf16x8 aq1 = *(const bf16x8*)(QKV + qO + 32 + quad * 8);

    bf16x8 ones8;
    #pragma unroll
    for (int j = 0; j < 8; j++) ones8[j] = (__bf16)1.0f;

    f32x4 o[4];
    #pragma unroll
    for (int dn = 0; dn < 4; dn++) o[dn] = (f32x4){0.f,0.f,0.f,0.f};
    f32x4 lsum = (f32x4){0.f,0.f,0.f,0.f};

    const int lrow = lane >> 2;                        // 0..15 (staging row)
    const int srcc8 = (((lane & 3) ^ (lrow & 3)) * 8); // swizzled source chunk (K)
    const int swz   = (quad ^ (col & 3)) * 8;          // swizzled K read chunk
    const size_t bS = (size_t)b * SEQ;

    // Hoisted per-lane stage pointers (advance by constant stride per tile).
    // Waves 0,1 stage K d-halves 0,1; waves 2,3 stage V d 0-31 / 32-63.
    const __bf16 *g0, *g1;
    size_t gstep;
    if (w < 2) {
        g0 = QKV + (bS + lrow) * QKVN + HIDDEN + kvh * HD + w * 32 + srcc8;
        g1 = g0 + (size_t)16 * QKVN;
        gstep = (size_t)32 * QKVN;
    } else {
        g0 = VT + (size_t)(kvh * HD + (w - 2) * 32 + lrow) * MROWS + bS + (lane & 3) * 8;
        g1 = g0 + (size_t)16 * MROWS;
        gstep = 32;
    }

    auto stage = [&](int sb) {
        if (w < 2) {
            gld16(g0, &Ks[sb][w][0][0]);
            gld16(g1, &Ks[sb][w][16][0]);
        } else {
            gld16(g0, &Vs[sb][(w - 2) * 32][0]);
            gld16(g1, &Vs[sb][(w - 2) * 32 + 16][0]);
        }
        g0 += gstep; g1 += gstep;
    };

    stage(0);
    stage(1);
    int cur = 0, nx2 = 2;
    for (int kt = 0; kt < n32; kt++) {
        const int kbase = kt * 32;
        // own stage(kt) landed (kt+1 still in flight); tail iterations drain
        if (kt + 1 < n32) { __asm__ volatile("s_waitcnt vmcnt(2)" ::: "memory"); }
        else              { __asm__ volatile("s_waitcnt vmcnt(0)" ::: "memory"); }
        __builtin_amdgcn_s_barrier();         // all waves' stage(kt) visible
        __asm__ volatile("" ::: "memory");
        if (kt + 2 < n32) stage(nx2);         // overwrites (kt-1)%3: safe post-barrier

        // S^T via swapped operands: lane holds S[qb+col][kbase+j*16+quad*4+r]
        f32x4 s[2];
        s[0] = (f32x4){0.f,0.f,0.f,0.f};
        s[1] = (f32x4){0.f,0.f,0.f,0.f};
        __builtin_amdgcn_s_setprio(1);
        #pragma unroll
        for (int j = 0; j < 2; j++) {
            bf16x8 bk0 = *(const bf16x8*)&Ks[cur][0][j*16 + col][swz];
            bf16x8 bk1 = *(const bf16x8*)&Ks[cur][1][j*16 + col][swz];
            s[j] = mfma32(bk0, aq0, s[j]);
            s[j] = mfma32(bk1, aq1, s[j]);
        }
        __builtin_amdgcn_s_setprio(0);

        // diagonal masking: k = kbase + j*16 + quad*4 + r vs q = qb + col
        if (kt >= n32 - 2) {
            #pragma unroll
            for (int j = 0; j < 2; j++)
                #pragma unroll
                for (int r = 0; r < 4; r++)
                    if (kbase + j*16 + quad*4 + r > qb + col) s[j][r] = -1e30f;
        }

        // P fully in-register as one K=32 A-fragment: elem e=j*4+r at hw k=quad*8+e
        bf16x8 pa;
        #pragma unroll
        for (int j = 0; j < 2; j++)
            #pragma unroll
            for (int r = 0; r < 4; r++)
                pa[j*4 + r] = (__bf16)__builtin_amdgcn_exp2f(s[j][r]);

        __builtin_amdgcn_s_setprio(1);
        lsum = mfma32(pa, ones8, lsum);       // rowsum, layout matches epilogue
        #pragma unroll
        for (int dn = 0; dn < 4; dn++) {
            bf16x8 bv = *(const bf16x8*)&Vs[cur][dn*16 + col][quad*8];
            o[dn] = mfma32(pa, bv, o[dn]);    // V sigma-permuted: one MFMA per dn
        }
        __builtin_amdgcn_s_setprio(0);

        cur = (cur == 2) ? 0 : cur + 1;
        nx2 = (nx2 == 2) ? 0 : nx2 + 1;
    }

    #pragma unroll
    for (int r = 0; r < 4; r++) {
        float inv = 1.0f / lsum[r];
        __bf16* op = O + (size_t)(b * SEQ + qb + quad*4 + r) * HIDDEN + head * HD;
        #pragma unroll
        for (int dn = 0; dn < 4; dn++)
            op[dn*16 + col] = (__bf16)(o[dn][r] * inv);
    }
}

// ---------------- launch ----------------
extern "C" void kernel_launch(void* const* d_in, const int* in_sizes, int n_in,
                              void* d_out, int out_size, void* d_ws, size_t ws_size,
                              hipStream_t stream) {
    const float* x  = (const float*)d_in[0];
    const float* Wq = (const float*)d_in[1];
    const float* Wk = (const float*)d_in[2];
    const float* Wv = (const float*)d_in[3];
    const float* Wo = (const float*)d_in[4];
    float* out = (float*)d_out;

    __bf16* p    = (__bf16*)d_ws;
    __bf16* xb   = p; p += (size_t)MROWS * HIDDEN;
    __bf16* wqkv = p; p += (size_t)QKVN * HIDDEN;
    __bf16* wob  = p; p += (size_t)HIDDEN * HIDDEN;
    __bf16* qkv  = p; p += (size_t)MROWS * QKVN;
    __bf16* vt   = p; p += (size_t)KVDIM * MROWS;
    __bf16* aob  = xb;   // alias: x not needed post-projection

    const float qscale = 0.125f * 1.4426950408889634f;
    cast_all<<<18432, 256, 0, stream>>>(x, Wq, Wk, Wv, Wo, xb, wqkv, wob, qscale);

    gemm256<<<dim3(QKVN/256, MROWS/256), 512, 0, stream>>>(xb, wqkv, qkv, MROWS, QKVN, HIDDEN);
    transpose_v<<<dim3(KVDIM/64, MROWS/64), dim3(256), 0, stream>>>(qkv, vt);
    flash_attn<<<BATCH * NHEADS * (SEQ/64), dim3(256), 0, stream>>>(qkv, vt, aob);
    gemm128<float><<<dim3(HIDDEN/128, MROWS/128), dim3(256), 0, stream>>>(aob, wob, out, MROWS, HIDDEN, HIDDEN);
}

// Round 7
// 271.672 us; speedup vs baseline: 1.2334x; 1.0307x over previous
//
#include <hip/hip_runtime.h>

#define HIDDEN 2048
#define NHEADS 32
#define NKV 8
#define HD 64
#define BATCH 2
#define SEQ 2048
#define MROWS (BATCH*SEQ)        // 4096
#define KVDIM (NKV*HD)           // 512
#define QKVN (HIDDEN + 2*KVDIM)  // 3072

typedef __bf16 bf16x8 __attribute__((ext_vector_type(8)));
typedef __bf16 bf16x4 __attribute__((ext_vector_type(4)));
typedef float f32x4 __attribute__((ext_vector_type(4)));

__device__ inline f32x4 mfma32(bf16x8 a, bf16x8 b, f32x4 c) {
    return __builtin_amdgcn_mfma_f32_16x16x32_bf16(a, b, c, 0, 0, 0);
}

// async global->LDS, 16B per lane; lds base must be wave-uniform (HW: base + lane*16)
__device__ inline void gld16(const __bf16* g, __bf16* l) {
    __builtin_amdgcn_global_load_lds((const __attribute__((address_space(1))) void*)g,
                                     (__attribute__((address_space(3))) void*)l, 16, 0, 0);
}

// ---------------- fused cast fp32 -> bf16 for all 5 tensors ----------------
__global__ __launch_bounds__(256) void cast_all(const float* __restrict__ x,
                                                const float* __restrict__ wq,
                                                const float* __restrict__ wk,
                                                const float* __restrict__ wv,
                                                const float* __restrict__ wo,
                                                __bf16* __restrict__ xb,
                                                __bf16* __restrict__ wqkv,
                                                __bf16* __restrict__ wob,
                                                float qscale) {
    int blk = blockIdx.x;
    const float* src; __bf16* dst; float sc = 1.0f; size_t off;
    if (blk < 8192)        { src = x;  dst = xb;   off = (size_t)blk * 1024; }
    else if (blk < 12288)  { src = wq; dst = wqkv; off = (size_t)(blk - 8192) * 1024; sc = qscale; }
    else if (blk < 13312)  { src = wk; dst = wqkv + (size_t)HIDDEN * HIDDEN; off = (size_t)(blk - 12288) * 1024; }
    else if (blk < 14336)  { src = wv; dst = wqkv + (size_t)(HIDDEN + KVDIM) * HIDDEN; off = (size_t)(blk - 13312) * 1024; }
    else                   { src = wo; dst = wob;  off = (size_t)(blk - 14336) * 1024; }
    size_t i4 = off + (size_t)threadIdx.x * 4;
    float4 f = *(const float4*)(src + i4);
    dst[i4 + 0] = (__bf16)(f.x * sc);
    dst[i4 + 1] = (__bf16)(f.y * sc);
    dst[i4 + 2] = (__bf16)(f.z * sc);
    dst[i4 + 3] = (__bf16)(f.w * sc);
}

__device__ inline void store_val(__bf16* C, size_t idx, float v) { C[idx] = (__bf16)v; }
__device__ inline void store_val(float* C, size_t idx, float v) { C[idx] = v; }

// ---------------- GEMM (gemm2): C = A(M,K) @ B(N,K)^T; 128^2, BK=32 ----------
template <typename OutT>
__global__ __launch_bounds__(256) void gemm128(const __bf16* __restrict__ A,
                                               const __bf16* __restrict__ B,
                                               OutT* __restrict__ C,
                                               int M, int N, int K) {
    __shared__ __bf16 As[2][128][32];
    __shared__ __bf16 Bs[2][128][32];
    const int tid  = threadIdx.x;
    const int lane = tid & 63;
    const int w    = tid >> 6;
    const int col  = lane & 15;
    const int quad = lane >> 4;
    const int m0 = blockIdx.y * 128;
    const int n0 = blockIdx.x * 128;
    const int wm = (w >> 1) * 64;
    const int wn = (w & 1) * 64;

    f32x4 acc[4][4];
    #pragma unroll
    for (int i = 0; i < 4; i++)
        #pragma unroll
        for (int j = 0; j < 4; j++) acc[i][j] = (f32x4){0.f,0.f,0.f,0.f};

    const int lrow = lane >> 2;        // 0..15
    const int lcol = (lane & 3) * 8;   // 0,8,16,24

    auto stage = [&](int k0, int buf) {
        #pragma unroll
        for (int c = 0; c < 4; c++) {
            int chunk = w * 4 + c;
            if (chunk < 8) {
                const __bf16* g = A + (size_t)(m0 + chunk*16 + lrow) * K + k0 + lcol;
                gld16(g, &As[buf][chunk*16][0]);
            } else {
                int bc = chunk - 8;
                const __bf16* g = B + (size_t)(n0 + bc*16 + lrow) * K + k0 + lcol;
                gld16(g, &Bs[buf][bc*16][0]);
            }
        }
    };

    const int nk = K / 32;
    stage(0, 0);
    for (int ki = 0; ki < nk; ki++) {
        const int buf = ki & 1;
        __syncthreads();                      // drains stage(ki) DMA; frees buf^1
        if (ki + 1 < nk) stage((ki + 1) * 32, buf ^ 1);   // overlaps compute below

        bf16x8 af[4], bfr[4];
        #pragma unroll
        for (int i = 0; i < 4; i++) af[i]  = *(const bf16x8*)&As[buf][wm + i*16 + col][quad*8];
        #pragma unroll
        for (int j = 0; j < 4; j++) bfr[j] = *(const bf16x8*)&Bs[buf][wn + j*16 + col][quad*8];
        #pragma unroll
        for (int i = 0; i < 4; i++)
            #pragma unroll
            for (int j = 0; j < 4; j++)
                acc[i][j] = __builtin_amdgcn_mfma_f32_16x16x32_bf16(af[i], bfr[j], acc[i][j], 0, 0, 0);
    }

    #pragma unroll
    for (int i = 0; i < 4; i++) {
        #pragma unroll
        for (int r = 0; r < 4; r++) {
            int mrow = m0 + wm + i*16 + quad*4 + r;
            size_t base = (size_t)mrow * N + n0 + wn;
            #pragma unroll
            for (int j = 0; j < 4; j++)
                store_val(C, base + j*16 + col, acc[i][j][r]);
        }
    }
}

// ---------------- GEMM (gemm1): 256x192 tile, BK=64, free-run pipeline --------
// R6 post-mortem: 8-barrier lockstep serialized {LDS-read burst | MFMA} with
// 1 block/CU -> ~5000 cyc/tile (LDS-issue-bound, MfmaUtil 30%, VALU 13%).
// This version: ONE s_barrier + ONE s_waitcnt vmcnt(0)+lgkmcnt(0) per K-tile;
// every operand subtile is ds_read one phase AHEAD (register prefetch), so the
// compiler's counted lgkm waits let reads drain UNDER the previous MFMA cluster
// and waves free-run within a tile.
// Quadrant order (mh0,b01)->(mh0,b2)->(mh1,b01)->(mh1,b2): each operand's last
// use precedes its next-tile re-read in wave program order -> single register
// banks (amh0 8, amh1 8, b01 4, b2 2 x b128 = 88 VGPR + 96 acc ~= 206, fits
// 2 waves/SIMD under __launch_bounds__(512,2)).
// Staging: whole-tile DMA batch (7 gld16/wave) issued at tile t for t+2; batch
// t+1 is a full tile old at the gate -> vmcnt(0) is ~free and t+2 loads stay in
// flight across the barrier (T4). Ledger:
//  - lgkmcnt(0) BEFORE the barrier forces all tile-t LDS reads into registers
//    (closes rule-18 hole: a sinking MFMA would let its read drift past the
//    barrier into the DMA overwrite window);
//  - all waves' tile-t reads therefore drain before barrier release, so the
//    post-barrier DMA batch (t+2 -> buf) is write-after-read safe;
//  - post-barrier prefetch reads (amh0/b01 of t+1) target buf^1, fully landed
//    (vmcnt gate + barrier), and no in-flight DMA targets buf^1 until t+1's
//    post-barrier batch -- after these reads drain at t+1's lgkmcnt(0).
// Swizzle (both-sides, rule #21): LDS chunk c at row r holds global chunk
// c ^ ((r>>1)&7); staged via pre-swizzled per-lane global source (dest linear),
// read back with the same XOR (r6: bank conflicts 6.3M -> 0).
// BN=192: grid (3072/192=16, 4096/256=16) = 256 blocks = exactly 1/CU.
// K accumulation order identical to gemm128 -> bit-identical C.
__global__ __launch_bounds__(512, 2) void gemm256(const __bf16* __restrict__ A,
                                                  const __bf16* __restrict__ B,
                                                  __bf16* __restrict__ C,
                                                  int M, int N, int K) {
    __shared__ __bf16 As[2][256][64];   // 64 KB
    __shared__ __bf16 Bs[2][192][64];   // 48 KB
    const int tid  = threadIdx.x;
    const int lane = tid & 63;
    const int w    = tid >> 6;       // 0..7
    const int wr   = w >> 2;         // 0..1 (M)
    const int wc   = w & 3;          // 0..3 (N)
    const int col  = lane & 15;
    const int quad = lane >> 4;
    const int m0 = blockIdx.y * 256;
    const int n0 = blockIdx.x * 192;
    const int nk = K >> 6;

    f32x4 acc[8][3];
    #pragma unroll
    for (int i = 0; i < 8; i++)
        #pragma unroll
        for (int j = 0; j < 3; j++) acc[i][j] = (f32x4){0.f,0.f,0.f,0.f};

    bf16x8 amh0[4][2];   // A rows wr*128 + 0..63    (used p0,p1)
    bf16x8 amh1[4][2];   // A rows wr*128 + 64..127  (used p2,p3)
    bf16x8 b01[2][2];    // B rows wc*48 + 0..31     (used p0,p2)
    bf16x8 b2v[2];       // B rows wc*48 + 32..47    (used p1,p3)

    // per-lane pre-swizzled staging sources; source chunk = c8 ^ ((ldsrow>>1)&7)
    const int r8 = lane >> 3, c8 = lane & 7;
    const __bf16* pA0 = A + (size_t)(m0 + w*16 +     r8) * K + ((c8 ^ quad) * 8);
    const __bf16* pA1 = A + (size_t)(m0 + w*16 + 8 + r8) * K + ((c8 ^ (4 + quad)) * 8);
    const __bf16* pB  = B + (size_t)(n0 + w*8 +      r8) * K + ((c8 ^ ((w & 1) * 4 + quad)) * 8);
    const int rsw = col >> 1;    // read-side swizzle term ((row>>1)&7 == col>>1 for all subtiles)

    auto issue = [&](int tt) {   // whole-tile staging batch: 7 gld16/wave
        if (tt < nk) {
            int b = tt & 1; size_t ko = (size_t)tt * 64;
            gld16(pA0 + ko,                  &As[b][w*16][0]);
            gld16(pA1 + ko,                  &As[b][w*16 + 8][0]);
            gld16(pA0 + (size_t)128*K + ko,  &As[b][128 + w*16][0]);
            gld16(pA1 + (size_t)128*K + ko,  &As[b][128 + w*16 + 8][0]);
            gld16(pB + ko,                   &Bs[b][w*8][0]);
            gld16(pB + (size_t)64*K + ko,    &Bs[b][64 + w*8][0]);
            gld16(pB + (size_t)128*K + ko,   &Bs[b][128 + w*8][0]);
        }
    };
    auto rdA = [&](bf16x8 (&dst)[4][2], int b, int rowbase) {
        #pragma unroll
        for (int i = 0; i < 4; i++) {
            const __bf16* rp = &As[b][rowbase + i*16 + col][0];
            #pragma unroll
            for (int kk = 0; kk < 2; kk++)
                dst[i][kk] = *(const bf16x8*)(rp + (((kk*4 + quad) ^ rsw) * 8));
        }
    };
    auto rdB01 = [&](int b) {
        #pragma unroll
        for (int j = 0; j < 2; j++) {
            const __bf16* rp = &Bs[b][wc*48 + j*16 + col][0];
            #pragma unroll
            for (int kk = 0; kk < 2; kk++)
                b01[j][kk] = *(const bf16x8*)(rp + (((kk*4 + quad) ^ rsw) * 8));
        }
    };

    // prologue: stage tiles 0 and 1; prefetch tile0's entry fragments
    issue(0); issue(1);
    __asm__ volatile("s_waitcnt vmcnt(7)" ::: "memory");   // tile0 landed (tile1 in flight)
    __builtin_amdgcn_s_barrier();
    __asm__ volatile("" ::: "memory");
    rdA(amh0, 0, wr*128);
    rdB01(0);

    for (int t = 0; t < nk; ++t) {
        const int buf = t & 1;
        // b2(t) read (drains under p0's MFMA via compiler counted lgkm)
        {
            const __bf16* rp = &Bs[buf][wc*48 + 32 + col][0];
            #pragma unroll
            for (int kk = 0; kk < 2; kk++)
                b2v[kk] = *(const bf16x8*)(rp + (((kk*4 + quad) ^ rsw) * 8));
        }
        // p0: amh0 x b01 (prefetched last tile)
        __builtin_amdgcn_s_setprio(1);
        #pragma unroll
        for (int i = 0; i < 4; i++)
            #pragma unroll
            for (int j = 0; j < 2; j++)
                #pragma unroll
                for (int kk = 0; kk < 2; kk++)
                    acc[i][j] = mfma32(amh0[i][kk], b01[j][kk], acc[i][j]);
        __builtin_amdgcn_s_setprio(0);
        // amh1(t) read (drains under p1)
        rdA(amh1, buf, wr*128 + 64);
        // p1: amh0 x b2
        __builtin_amdgcn_s_setprio(1);
        #pragma unroll
        for (int i = 0; i < 4; i++)
            #pragma unroll
            for (int kk = 0; kk < 2; kk++)
                acc[i][2] = mfma32(amh0[i][kk], b2v[kk], acc[i][2]);
        __builtin_amdgcn_s_setprio(0);
        // p2: amh1 x b01
        __builtin_amdgcn_s_setprio(1);
        #pragma unroll
        for (int i = 0; i < 4; i++)
            #pragma unroll
            for (int j = 0; j < 2; j++)
                #pragma unroll
                for (int kk = 0; kk < 2; kk++)
                    acc[4+i][j] = mfma32(amh1[i][kk], b01[j][kk], acc[4+i][j]);
        __builtin_amdgcn_s_setprio(0);

        // tile boundary: all tile-t LDS reads into regs + tile t+1 staged (own
        // wave), then barrier makes both global across waves.
        __asm__ volatile("s_waitcnt vmcnt(0) lgkmcnt(0)" ::: "memory");
        __builtin_amdgcn_sched_barrier(0);
        __builtin_amdgcn_s_barrier();
        __asm__ volatile("" ::: "memory");

        // prefetch tile t+1 entry fragments from buf^1 (landed + barrier'd)
        if (t + 1 < nk) {
            rdA(amh0, buf ^ 1, wr*128);
            rdB01(buf ^ 1);
        }
        issue(t + 2);    // stage tile t+2 into buf (all tile-t reads drained)

        // p3: amh1 x b2 (register-only; may float around reads/issues)
        __builtin_amdgcn_s_setprio(1);
        #pragma unroll
        for (int i = 0; i < 4; i++)
            #pragma unroll
            for (int kk = 0; kk < 2; kk++)
                acc[4+i][2] = mfma32(amh1[i][kk], b2v[kk], acc[4+i][2]);
        __builtin_amdgcn_s_setprio(0);
    }

    #pragma unroll
    for (int i16 = 0; i16 < 8; i16++) {
        #pragma unroll
        for (int r = 0; r < 4; r++) {
            size_t base = (size_t)(m0 + wr*128 + i16*16 + quad*4 + r) * N + n0 + wc*48;
            #pragma unroll
            for (int j = 0; j < 3; j++)
                C[base + j*16 + col] = (__bf16)acc[i16][j][r];
        }
    }
}

// ---------------- V transpose with k-order permutation -----------------------
// VT[d][32-block B][o] = V[s = 32B + sigma(o)][d], sigma: o=Q*8+e -> (e>>2)*16+Q*4+(e&3).
// A ds_read_b128 at [d][quad*8] in flash yields the B-fragment of a K=32 MFMA
// whose A operand is the in-register P fragment -- zero cross-lane.
__global__ __launch_bounds__(256) void transpose_v(const __bf16* __restrict__ QKV,
                                                   __bf16* __restrict__ VT) {
    __shared__ __bf16 tile[64][72];
    const int r0 = blockIdx.x * 64;
    const int s0 = blockIdx.y * 64;
    const int t  = threadIdx.x;
    #pragma unroll
    for (int cc = 0; cc < 2; cc++) {
        int c = t + cc * 256;
        int i = c >> 3;
        int j8 = (c & 7) * 8;
        bf16x8 v = *(const bf16x8*)(QKV + (size_t)(s0 + i) * QKVN + (HIDDEN + KVDIM) + r0 + j8);
        *(bf16x8*)&tile[i][j8] = v;
    }
    __syncthreads();
    #pragma unroll
    for (int cc = 0; cc < 2; cc++) {
        int c = t + cc * 256;
        int d = c >> 3;
        int m = c & 7;                 // output 8-elem chunk within 64 s-positions
        bf16x8 vv;
        #pragma unroll
        for (int tt = 0; tt < 8; tt++) {
            // out offset o=8m+tt -> s_local = (m>>2)*32 + (tt>>2)*16 + (m&3)*4 + (tt&3)
            int sl = (m >> 2) * 32 + (tt >> 2) * 16 + (m & 3) * 4 + (tt & 3);
            vv[tt] = tile[sl][d];
        }
        *(bf16x8*)(VT + (size_t)(r0 + d) * MROWS + s0 + m * 8) = vv;
    }
}

// ---------------- flash attention: single-tile blocks, all-K=32, 3-buf K/V ----
// One block per (batch, head, 64-row q-tile): 2048 blocks, longest-first.
// QK^T swapped (mfma(K,Q)); P = exp2(S) packed in-register to ONE bf16x8 and
// fed to K=32 MFMAs for PV (V sigma-permuted) and the ones-rowsum.
// Ks/Vs triple-buffered; raw s_barrier + counted s_waitcnt vmcnt(2).
// Q pre-scaled by (1/8)*log2(e); fixed-max exp2 softmax.
__global__ __launch_bounds__(256) void flash_attn(const __bf16* __restrict__ QKV,
                                                  const __bf16* __restrict__ VT,
                                                  __bf16* __restrict__ O) {
    const int bid  = blockIdx.x;
    const int t    = 31 - (bid >> 6);         // q-tile index, longest first
    const int head = (bid >> 1) & 31;
    const int b    = bid & 1;
    const int kvh  = head >> 2;
    const int tid  = threadIdx.x;
    const int lane = tid & 63;
    const int w    = tid >> 6;
    const int col  = lane & 15;
    const int quad = lane >> 4;

    const int qb   = t * 64 + w * 16;         // this wave's 16 q-rows
    const int n32  = (t + 1) * 2;             // k-tiles (32-granular), >=2

    __shared__ __bf16 Ks[3][2][32][32];  // [buf][d-half][kpos][d32]  12 KB
    __shared__ __bf16 Vs[3][64][32];     // [buf][d][k-perm o]        12 KB

    const size_t qO = (size_t)(b * SEQ + qb + col) * QKVN + head * HD;
    bf16x8 aq0 = *(const bf16x8*)(QKV + qO + quad * 8);
    bf16x8 aq1 = *(const bf16x8*)(QKV + qO + 32 + quad * 8);

    bf16x8 ones8;
    #pragma unroll
    for (int j = 0; j < 8; j++) ones8[j] = (__bf16)1.0f;

    f32x4 o[4];
    #pragma unroll
    for (int dn = 0; dn < 4; dn++) o[dn] = (f32x4){0.f,0.f,0.f,0.f};
    f32x4 lsum = (f32x4){0.f,0.f,0.f,0.f};

    const int lrow = lane >> 2;                        // 0..15 (staging row)
    const int srcc8 = (((lane & 3) ^ (lrow & 3)) * 8); // swizzled source chunk (K)
    const int swz   = (quad ^ (col & 3)) * 8;          // swizzled K read chunk
    const size_t bS = (size_t)b * SEQ;

    // Hoisted per-lane stage pointers (advance by constant stride per tile).
    // Waves 0,1 stage K d-halves 0,1; waves 2,3 stage V d 0-31 / 32-63.
    const __bf16 *g0, *g1;
    size_t gstep;
    if (w < 2) {
        g0 = QKV + (bS + lrow) * QKVN + HIDDEN + kvh * HD + w * 32 + srcc8;
        g1 = g0 + (size_t)16 * QKVN;
        gstep = (size_t)32 * QKVN;
    } else {
        g0 = VT + (size_t)(kvh * HD + (w - 2) * 32 + lrow) * MROWS + bS + (lane & 3) * 8;
        g1 = g0 + (size_t)16 * MROWS;
        gstep = 32;
    }

    auto stage = [&](int sb) {
        if (w < 2) {
            gld16(g0, &Ks[sb][w][0][0]);
            gld16(g1, &Ks[sb][w][16][0]);
        } else {
            gld16(g0, &Vs[sb][(w - 2) * 32][0]);
            gld16(g1, &Vs[sb][(w - 2) * 32 + 16][0]);
        }
        g0 += gstep; g1 += gstep;
    };

    stage(0);
    stage(1);
    int cur = 0, nx2 = 2;
    for (int kt = 0; kt < n32; kt++) {
        const int kbase = kt * 32;
        // own stage(kt) landed (kt+1 still in flight); tail iterations drain
        if (kt + 1 < n32) { __asm__ volatile("s_waitcnt vmcnt(2)" ::: "memory"); }
        else              { __asm__ volatile("s_waitcnt vmcnt(0)" ::: "memory"); }
        __builtin_amdgcn_s_barrier();         // all waves' stage(kt) visible
        __asm__ volatile("" ::: "memory");
        if (kt + 2 < n32) stage(nx2);         // overwrites (kt-1)%3: safe post-barrier

        // S^T via swapped operands: lane holds S[qb+col][kbase+j*16+quad*4+r]
        f32x4 s[2];
        s[0] = (f32x4){0.f,0.f,0.f,0.f};
        s[1] = (f32x4){0.f,0.f,0.f,0.f};
        __builtin_amdgcn_s_setprio(1);
        #pragma unroll
        for (int j = 0; j < 2; j++) {
            bf16x8 bk0 = *(const bf16x8*)&Ks[cur][0][j*16 + col][swz];
            bf16x8 bk1 = *(const bf16x8*)&Ks[cur][1][j*16 + col][swz];
            s[j] = mfma32(bk0, aq0, s[j]);
            s[j] = mfma32(bk1, aq1, s[j]);
        }
        __builtin_amdgcn_s_setprio(0);

        // diagonal masking: k = kbase + j*16 + quad*4 + r vs q = qb + col
        if (kt >= n32 - 2) {
            #pragma unroll
            for (int j = 0; j < 2; j++)
                #pragma unroll
                for (int r = 0; r < 4; r++)
                    if (kbase + j*16 + quad*4 + r > qb + col) s[j][r] = -1e30f;
        }

        // P fully in-register as one K=32 A-fragment: elem e=j*4+r at hw k=quad*8+e
        bf16x8 pa;
        #pragma unroll
        for (int j = 0; j < 2; j++)
            #pragma unroll
            for (int r = 0; r < 4; r++)
                pa[j*4 + r] = (__bf16)__builtin_amdgcn_exp2f(s[j][r]);

        __builtin_amdgcn_s_setprio(1);
        lsum = mfma32(pa, ones8, lsum);       // rowsum, layout matches epilogue
        #pragma unroll
        for (int dn = 0; dn < 4; dn++) {
            bf16x8 bv = *(const bf16x8*)&Vs[cur][dn*16 + col][quad*8];
            o[dn] = mfma32(pa, bv, o[dn]);    // V sigma-permuted: one MFMA per dn
        }
        __builtin_amdgcn_s_setprio(0);

        cur = (cur == 2) ? 0 : cur + 1;
        nx2 = (nx2 == 2) ? 0 : nx2 + 1;
    }

    #pragma unroll
    for (int r = 0; r < 4; r++) {
        float inv = 1.0f / lsum[r];
        __bf16* op = O + (size_t)(b * SEQ + qb + quad*4 + r) * HIDDEN + head * HD;
        #pragma unroll
        for (int dn = 0; dn < 4; dn++)
            op[dn*16 + col] = (__bf16)(o[dn][r] * inv);
    }
}

// ---------------- launch ----------------
extern "C" void kernel_launch(void* const* d_in, const int* in_sizes, int n_in,
                              void* d_out, int out_size, void* d_ws, size_t ws_size,
                              hipStream_t stream) {
    const float* x  = (const float*)d_in[0];
    const float* Wq = (const float*)d_in[1];
    const float* Wk = (const float*)d_in[2];
    const float* Wv = (const float*)d_in[3];
    const float* Wo = (const float*)d_in[4];
    float* out = (float*)d_out;

    __bf16* p    = (__bf16*)d_ws;
    __bf16* xb   = p; p += (size_t)MROWS * HIDDEN;
    __bf16* wqkv = p; p += (size_t)QKVN * HIDDEN;
    __bf16* wob  = p; p += (size_t)HIDDEN * HIDDEN;
    __bf16* qkv  = p; p += (size_t)MROWS * QKVN;
    __bf16* vt   = p; p += (size_t)KVDIM * MROWS;
    __bf16* aob  = xb;   // alias: x not needed post-projection

    const float qscale = 0.125f * 1.4426950408889634f;
    cast_all<<<18432, 256, 0, stream>>>(x, Wq, Wk, Wv, Wo, xb, wqkv, wob, qscale);

    gemm256<<<dim3(QKVN/192, MROWS/256), 512, 0, stream>>>(xb, wqkv, qkv, MROWS, QKVN, HIDDEN);
    transpose_v<<<dim3(KVDIM/64, MROWS/64), dim3(256), 0, stream>>>(qkv, vt);
    flash_attn<<<BATCH * NHEADS * (SEQ/64), dim3(256), 0, stream>>>(qkv, vt, aob);
    gemm128<float><<<dim3(HIDDEN/128, MROWS/128), dim3(256), 0, stream>>>(aob, wob, out, MROWS, HIDDEN, HIDDEN);
}